// Round 1
// baseline (2263.936 us; speedup 1.0000x reference)
//
#include <hip/hip_runtime.h>

#define NF 128   // in/hidden features
#define NC 64    // classes

__device__ __forceinline__ void atomAddF(float* p, float v) {
    unsafeAtomicAdd(p, v);   // HW global_atomic_add_f32 on gfx950
}

// ---- degree: deg[col[e]] += ew[e] ----
__global__ __launch_bounds__(256) void deg_kernel(const int* __restrict__ col,
                                                  const float* __restrict__ ew,
                                                  float* __restrict__ deg, int E) {
    int e = blockIdx.x * 256 + threadIdx.x;
    if (e < E) atomAddF(&deg[col[e]], ew[e]);
}

// ---- dinv = rsqrt(deg + 1)  (self-loop weight 1.0 folded in) ----
__global__ __launch_bounds__(256) void dinv_kernel(const float* __restrict__ deg,
                                                   float* __restrict__ dinv, int N) {
    int n = blockIdx.x * 256 + threadIdx.x;
    if (n < N) {
        float d = deg[n] + 1.0f;
        dinv[n] = d > 0.0f ? rsqrtf(d) : 0.0f;
    }
}

// ---- H = X @ W, K=128 fixed, MOUT in {128,64}; 64-col W tile in LDS ----
template<int MOUT>
__global__ __launch_bounds__(256) void gemm_k128(const float* __restrict__ X,
                                                 const float* __restrict__ W,
                                                 float* __restrict__ H, int N) {
    __shared__ float Ws[128 * 64];
    const int m0 = blockIdx.y * 64;
    for (int i = threadIdx.x; i < 128 * 64; i += 256) {
        int k = i >> 6, mm = i & 63;
        Ws[i] = W[k * MOUT + m0 + mm];
    }
    __syncthreads();
    const int mm = threadIdx.x & 63;
    const int g  = threadIdx.x >> 6;       // 4 node-groups per block
    const int base = blockIdx.x * 16 + g * 4;
    const float4* X4 = (const float4*)X;
    int n0 = min(base + 0, N - 1), n1 = min(base + 1, N - 1);
    int n2 = min(base + 2, N - 1), n3 = min(base + 3, N - 1);
    float acc0 = 0.f, acc1 = 0.f, acc2 = 0.f, acc3 = 0.f;
#pragma unroll 4
    for (int k4 = 0; k4 < 32; ++k4) {
        float4 x0 = X4[n0 * 32 + k4], x1 = X4[n1 * 32 + k4];
        float4 x2 = X4[n2 * 32 + k4], x3 = X4[n3 * 32 + k4];
        float w;
        w = Ws[(k4 * 4 + 0) * 64 + mm]; acc0 += x0.x * w; acc1 += x1.x * w; acc2 += x2.x * w; acc3 += x3.x * w;
        w = Ws[(k4 * 4 + 1) * 64 + mm]; acc0 += x0.y * w; acc1 += x1.y * w; acc2 += x2.y * w; acc3 += x3.y * w;
        w = Ws[(k4 * 4 + 2) * 64 + mm]; acc0 += x0.z * w; acc1 += x1.z * w; acc2 += x2.z * w; acc3 += x3.z * w;
        w = Ws[(k4 * 4 + 3) * 64 + mm]; acc0 += x0.w * w; acc1 += x1.w * w; acc2 += x2.w * w; acc3 += x3.w * w;
    }
    if (base + 0 < N) H[(long long)(base + 0) * MOUT + m0 + mm] = acc0;
    if (base + 1 < N) H[(long long)(base + 1) * MOUT + m0 + mm] = acc1;
    if (base + 2 < N) H[(long long)(base + 2) * MOUT + m0 + mm] = acc2;
    if (base + 3 < N) H[(long long)(base + 3) * MOUT + m0 + mm] = acc3;
}

// ---- edge aggregation: agg[col] += dinv[row]*ew*dinv[col] * H[row]; F4 lanes/edge ----
template<int F4>
__global__ __launch_bounds__(256) void agg_edges(const int* __restrict__ row,
                                                 const int* __restrict__ col,
                                                 const float* __restrict__ ew,
                                                 const float* __restrict__ dinv,
                                                 const float4* __restrict__ H4,
                                                 float* __restrict__ agg, int E) {
    int tid = blockIdx.x * 256 + threadIdx.x;
    int e = tid / F4, j = tid % F4;
    if (e >= E) return;
    int r = row[e], c = col[e];
    float w = dinv[r] * ew[e] * dinv[c];
    float4 v = H4[r * F4 + j];
    float* dst = agg + ((long long)c * F4 + j) * 4;
    atomAddF(dst + 0, w * v.x);
    atomAddF(dst + 1, w * v.y);
    atomAddF(dst + 2, w * v.z);
    atomAddF(dst + 3, w * v.w);
}

// ---- out = relu(agg + dinv^2 * h + b), in place into agg (layer 1 epilogue) ----
__global__ __launch_bounds__(256) void relu_bias_self(float4* __restrict__ agg,
                                                      const float4* __restrict__ h,
                                                      const float* __restrict__ dinv,
                                                      const float4* __restrict__ b, int N) {
    int i = blockIdx.x * 256 + threadIdx.x;
    if (i >= N * (NF / 4)) return;
    int n = i >> 5, f = i & 31;
    float s = dinv[n]; s *= s;
    float4 a = agg[i], hv = h[i], bv = b[f];
    float4 o;
    o.x = fmaxf(fmaf(s, hv.x, a.x) + bv.x, 0.f);
    o.y = fmaxf(fmaf(s, hv.y, a.y) + bv.y, 0.f);
    o.z = fmaxf(fmaf(s, hv.z, a.z) + bv.z, 0.f);
    o.w = fmaxf(fmaf(s, hv.w, a.w) + bv.w, 0.f);
    agg[i] = o;
}

// ---- layer-2 epilogue + row L2 normalize: one 64-lane wave per node ----
__global__ __launch_bounds__(256) void finalize_kernel(const float* __restrict__ agg,
                                                       const float* __restrict__ h,
                                                       const float* __restrict__ dinv,
                                                       const float* __restrict__ b,
                                                       float* __restrict__ out, int N) {
    int i = blockIdx.x * 256 + threadIdx.x;
    bool ok = i < N * NC;
    int n = min(i >> 6, N - 1), f = i & 63;
    float s = dinv[n]; s *= s;
    float v = ok ? (agg[i] + s * h[i] + b[f]) : 0.0f;
    float ss = v * v;
#pragma unroll
    for (int off = 32; off; off >>= 1) ss += __shfl_xor(ss, off, 64);
    float nrm = sqrtf(ss);
    float scale = 1.0f / fmaxf(nrm, 1e-12f);
    if (ok) out[i] = v * scale;
}

extern "C" void kernel_launch(void* const* d_in, const int* in_sizes, int n_in,
                              void* d_out, int out_size, void* d_ws, size_t ws_size,
                              hipStream_t stream) {
    const float* x  = (const float*)d_in[0];
    const int*   ei = (const int*)d_in[1];
    const float* ew = (const float*)d_in[2];
    const float* W1 = (const float*)d_in[3];
    const float* b1 = (const float*)d_in[4];
    const float* W2 = (const float*)d_in[5];
    const float* b2 = (const float*)d_in[6];
    float* out = (float*)d_out;
    const int N = in_sizes[0] / NF;
    const int E = in_sizes[2];
    const int* row = ei;
    const int* col = ei + E;

    char* ws = (char*)d_ws;
    size_t off = 0;
    auto take = [&](size_t bytes) {
        char* p = ws + off;
        off = (off + bytes + 255) & ~(size_t)255;
        return p;
    };
    float* deg  = (float*)take((size_t)N * 4);
    float* dinv = (float*)take((size_t)N * 4);
    float* buf1 = (float*)take((size_t)N * NF * 4);   // H1, later H3 | agg2
    float* buf2 = (float*)take((size_t)N * NF * 4);   // agg1 -> relu output
    float* h3   = buf1;                                // N*NC
    float* agg2 = buf1 + (size_t)N * NC;               // N*NC (disjoint from h3)

    hipMemsetAsync(deg, 0, (size_t)N * 4, stream);
    deg_kernel<<<(E + 255) / 256, 256, 0, stream>>>(col, ew, deg, E);
    dinv_kernel<<<(N + 255) / 256, 256, 0, stream>>>(deg, dinv, N);

    // layer 1
    gemm_k128<NF><<<dim3((N + 15) / 16, NF / 64), 256, 0, stream>>>(x, W1, buf1, N);
    hipMemsetAsync(buf2, 0, (size_t)N * NF * 4, stream);
    agg_edges<NF / 4><<<(int)(((long long)E * (NF / 4) + 255) / 256), 256, 0, stream>>>(
        row, col, ew, dinv, (const float4*)buf1, buf2, E);
    relu_bias_self<<<(N * (NF / 4) + 255) / 256, 256, 0, stream>>>(
        (float4*)buf2, (const float4*)buf1, dinv, (const float4*)b1, N);

    // layer 2
    gemm_k128<NC><<<dim3((N + 15) / 16, NC / 64), 256, 0, stream>>>(buf2, W2, h3, N);
    hipMemsetAsync(agg2, 0, (size_t)N * NC * 4, stream);
    agg_edges<NC / 4><<<(int)(((long long)E * (NC / 4) + 255) / 256), 256, 0, stream>>>(
        row, col, ew, dinv, (const float4*)h3, agg2, E);
    finalize_kernel<<<(N * NC + 255) / 256, 256, 0, stream>>>(agg2, h3, dinv, b2, out, N);
}

// Round 2
// 420.269 us; speedup vs baseline: 5.3869x; 5.3869x over previous
//
#include <hip/hip_runtime.h>

#define NF 128   // in/hidden features
#define NC 64    // classes

// ---- degree (weighted, fp32) + in-edge count (int) per destination ----
__global__ __launch_bounds__(256) void deg_count_kernel(const int* __restrict__ col,
                                                        const float* __restrict__ ew,
                                                        float* __restrict__ deg,
                                                        int* __restrict__ cnt, int E) {
    int e = blockIdx.x * 256 + threadIdx.x;
    if (e < E) {
        int c = col[e];
        unsafeAtomicAdd(&deg[c], ew[e]);
        atomicAdd(&cnt[c], 1);
    }
}

// ---- dinv = rsqrt(deg + 1)  (self-loop weight 1.0 folded in) ----
__global__ __launch_bounds__(256) void dinv_kernel(const float* __restrict__ deg,
                                                   float* __restrict__ dinv, int N) {
    int n = blockIdx.x * 256 + threadIdx.x;
    if (n < N) {
        float d = deg[n] + 1.0f;
        dinv[n] = d > 0.0f ? rsqrtf(d) : 0.0f;
    }
}

// ---- exclusive scan of cnt[N] -> rowPtr[N+1], 1024 elems/block ----
__global__ __launch_bounds__(256) void scan_blocks(const int* __restrict__ cnt,
                                                   int* __restrict__ excl,
                                                   int* __restrict__ bsum, int N) {
    __shared__ int sh[256];
    int t = threadIdx.x;
    int base = blockIdx.x * 1024 + t * 4;
    int v0 = base + 0 < N ? cnt[base + 0] : 0;
    int v1 = base + 1 < N ? cnt[base + 1] : 0;
    int v2 = base + 2 < N ? cnt[base + 2] : 0;
    int v3 = base + 3 < N ? cnt[base + 3] : 0;
    int s = v0 + v1 + v2 + v3;
    sh[t] = s;
    __syncthreads();
    for (int off = 1; off < 256; off <<= 1) {
        int x = (t >= off) ? sh[t - off] : 0;
        __syncthreads();
        sh[t] += x;
        __syncthreads();
    }
    int incl = sh[t];
    int exclT = incl - s;
    if (t == 255) bsum[blockIdx.x] = incl;
    if (base + 0 < N) excl[base + 0] = exclT;
    if (base + 1 < N) excl[base + 1] = exclT + v0;
    if (base + 2 < N) excl[base + 2] = exclT + v0 + v1;
    if (base + 3 < N) excl[base + 3] = exclT + v0 + v1 + v2;
}

__global__ void scan_sums(int* __restrict__ bsum, int nb) {
    // single thread; nb ~ 49
    int run = 0;
    for (int i = 0; i < nb; ++i) { int v = bsum[i]; bsum[i] = run; run += v; }
    bsum[nb] = run;
}

__global__ __launch_bounds__(256) void scan_add(int* __restrict__ excl,
                                                const int* __restrict__ bsum,
                                                int N, int nb) {
    int i = blockIdx.x * 256 + threadIdx.x;
    if (i < N) excl[i] += bsum[i >> 10];
    if (i == 0) excl[N] = bsum[nb];
}

// ---- scatter edges into CSR (by col), precomputing normalized weight ----
__global__ __launch_bounds__(256) void scatter_kernel(const int* __restrict__ row,
                                                      const int* __restrict__ col,
                                                      const float* __restrict__ ew,
                                                      const float* __restrict__ dinv,
                                                      const int* __restrict__ rowPtr,
                                                      int* __restrict__ cursor,
                                                      int* __restrict__ csr_src,
                                                      float* __restrict__ csr_w, int E) {
    int e = blockIdx.x * 256 + threadIdx.x;
    if (e >= E) return;
    int r = row[e], c = col[e];
    int pos = atomicAdd(&cursor[c], 1);
    int idx = rowPtr[c] + pos;
    csr_src[idx] = r;
    csr_w[idx] = dinv[r] * ew[e] * dinv[c];
}

// ---- H = X @ W, K=128 fixed, MOUT in {128,64}; 64-col W tile in LDS ----
template<int MOUT>
__global__ __launch_bounds__(256) void gemm_k128(const float* __restrict__ X,
                                                 const float* __restrict__ W,
                                                 float* __restrict__ H, int N) {
    __shared__ float Ws[128 * 64];
    const int m0 = blockIdx.y * 64;
    for (int i = threadIdx.x; i < 128 * 64; i += 256) {
        int k = i >> 6, mm = i & 63;
        Ws[i] = W[k * MOUT + m0 + mm];
    }
    __syncthreads();
    const int mm = threadIdx.x & 63;
    const int g  = threadIdx.x >> 6;
    const int base = blockIdx.x * 16 + g * 4;
    const float4* X4 = (const float4*)X;
    int n0 = min(base + 0, N - 1), n1 = min(base + 1, N - 1);
    int n2 = min(base + 2, N - 1), n3 = min(base + 3, N - 1);
    float acc0 = 0.f, acc1 = 0.f, acc2 = 0.f, acc3 = 0.f;
#pragma unroll 4
    for (int k4 = 0; k4 < 32; ++k4) {
        float4 x0 = X4[n0 * 32 + k4], x1 = X4[n1 * 32 + k4];
        float4 x2 = X4[n2 * 32 + k4], x3 = X4[n3 * 32 + k4];
        float w;
        w = Ws[(k4 * 4 + 0) * 64 + mm]; acc0 += x0.x * w; acc1 += x1.x * w; acc2 += x2.x * w; acc3 += x3.x * w;
        w = Ws[(k4 * 4 + 1) * 64 + mm]; acc0 += x0.y * w; acc1 += x1.y * w; acc2 += x2.y * w; acc3 += x3.y * w;
        w = Ws[(k4 * 4 + 2) * 64 + mm]; acc0 += x0.z * w; acc1 += x1.z * w; acc2 += x2.z * w; acc3 += x3.z * w;
        w = Ws[(k4 * 4 + 3) * 64 + mm]; acc0 += x0.w * w; acc1 += x1.w * w; acc2 += x2.w * w; acc3 += x3.w * w;
    }
    if (base + 0 < N) H[(long long)(base + 0) * MOUT + m0 + mm] = acc0;
    if (base + 1 < N) H[(long long)(base + 1) * MOUT + m0 + mm] = acc1;
    if (base + 2 < N) H[(long long)(base + 2) * MOUT + m0 + mm] = acc2;
    if (base + 3 < N) H[(long long)(base + 3) * MOUT + m0 + mm] = acc3;
}

// ---- layer 1 gather-aggregate + self + bias + relu. One wave per node, lane=float2 ----
__global__ __launch_bounds__(256) void agg_gather1(const int* __restrict__ rowPtr,
                                                   const int* __restrict__ csr_src,
                                                   const float* __restrict__ csr_w,
                                                   const float2* __restrict__ H2,
                                                   const float* __restrict__ dinv,
                                                   const float2* __restrict__ b2,
                                                   float2* __restrict__ out2, int N) {
    int wave = (blockIdx.x * 256 + threadIdx.x) >> 6;
    int lane = threadIdx.x & 63;
    if (wave >= N) return;
    const int n = wave;
    const int F2 = NF / 2;
    float s = dinv[n]; s *= s;
    float2 h = H2[(size_t)n * F2 + lane];
    float accx = s * h.x, accy = s * h.y;
    int beg = rowPtr[n], end = rowPtr[n + 1];
    for (int base = beg; base < end; base += 64) {
        int i = base + lane;
        int   r_l = i < end ? csr_src[i] : 0;
        float w_l = i < end ? csr_w[i] : 0.f;
        int m = min(end - base, 64);
        for (int j = 0; j < m; ++j) {
            int   r = __shfl(r_l, j, 64);
            float w = __shfl(w_l, j, 64);
            float2 v = H2[(size_t)r * F2 + lane];
            accx += w * v.x;
            accy += w * v.y;
        }
    }
    float2 bb = b2[lane];
    float2 o;
    o.x = fmaxf(accx + bb.x, 0.f);
    o.y = fmaxf(accy + bb.y, 0.f);
    out2[(size_t)n * F2 + lane] = o;
}

// ---- layer 2 gather-aggregate + self + bias + L2 normalize. One wave per node, lane=1 float ----
__global__ __launch_bounds__(256) void agg_gather2(const int* __restrict__ rowPtr,
                                                   const int* __restrict__ csr_src,
                                                   const float* __restrict__ csr_w,
                                                   const float* __restrict__ H,
                                                   const float* __restrict__ dinv,
                                                   const float* __restrict__ b,
                                                   float* __restrict__ out, int N) {
    int wave = (blockIdx.x * 256 + threadIdx.x) >> 6;
    int lane = threadIdx.x & 63;
    if (wave >= N) return;
    const int n = wave;
    float s = dinv[n]; s *= s;
    float acc = s * H[(size_t)n * NC + lane];
    int beg = rowPtr[n], end = rowPtr[n + 1];
    for (int base = beg; base < end; base += 64) {
        int i = base + lane;
        int   r_l = i < end ? csr_src[i] : 0;
        float w_l = i < end ? csr_w[i] : 0.f;
        int m = min(end - base, 64);
        for (int j = 0; j < m; ++j) {
            int   r = __shfl(r_l, j, 64);
            float w = __shfl(w_l, j, 64);
            acc += w * H[(size_t)r * NC + lane];
        }
    }
    acc += b[lane];
    float ss = acc * acc;
#pragma unroll
    for (int off = 32; off; off >>= 1) ss += __shfl_xor(ss, off, 64);
    float scale = 1.0f / fmaxf(sqrtf(ss), 1e-12f);
    out[(size_t)n * NC + lane] = acc * scale;
}

extern "C" void kernel_launch(void* const* d_in, const int* in_sizes, int n_in,
                              void* d_out, int out_size, void* d_ws, size_t ws_size,
                              hipStream_t stream) {
    const float* x  = (const float*)d_in[0];
    const int*   ei = (const int*)d_in[1];
    const float* ew = (const float*)d_in[2];
    const float* W1 = (const float*)d_in[3];
    const float* b1 = (const float*)d_in[4];
    const float* W2 = (const float*)d_in[5];
    const float* b2 = (const float*)d_in[6];
    float* out = (float*)d_out;
    const int N = in_sizes[0] / NF;
    const int E = in_sizes[2];
    const int* row = ei;
    const int* col = ei + E;
    const int NB = (N + 1023) / 1024;

    char* ws = (char*)d_ws;
    size_t off = 0;
    auto take = [&](size_t bytes) {
        char* p = ws + off;
        off = (off + bytes + 255) & ~(size_t)255;
        return p;
    };
    float* deg     = (float*)take((size_t)N * 4);
    float* dinv    = (float*)take((size_t)N * 4);
    int*   cnt     = (int*)  take((size_t)N * 4);
    int*   rowPtr  = (int*)  take((size_t)(N + 1) * 4);
    int*   cursor  = (int*)  take((size_t)N * 4);
    int*   bsum    = (int*)  take((size_t)(NB + 1) * 4);
    int*   csr_src = (int*)  take((size_t)E * 4);
    float* csr_w   = (float*)take((size_t)E * 4);
    float* buf1    = (float*)take((size_t)N * NF * 4);  // H1, later H3 (N*NC)
    float* buf2    = (float*)take((size_t)N * NF * 4);  // relu output

    hipMemsetAsync(deg, 0, (size_t)N * 4, stream);
    hipMemsetAsync(cnt, 0, (size_t)N * 4, stream);
    hipMemsetAsync(cursor, 0, (size_t)N * 4, stream);

    // degree + counts, dinv
    deg_count_kernel<<<(E + 255) / 256, 256, 0, stream>>>(col, ew, deg, cnt, E);
    dinv_kernel<<<(N + 255) / 256, 256, 0, stream>>>(deg, dinv, N);

    // CSR build
    scan_blocks<<<NB, 256, 0, stream>>>(cnt, rowPtr, bsum, N);
    scan_sums<<<1, 1, 0, stream>>>(bsum, NB);
    scan_add<<<(N + 255) / 256, 256, 0, stream>>>(rowPtr, bsum, N, NB);
    scatter_kernel<<<(E + 255) / 256, 256, 0, stream>>>(row, col, ew, dinv, rowPtr,
                                                        cursor, csr_src, csr_w, E);

    // layer 1: H1 = X@W1 ; agg+self+bias+relu -> buf2
    gemm_k128<NF><<<dim3((N + 15) / 16, NF / 64), 256, 0, stream>>>(x, W1, buf1, N);
    agg_gather1<<<(N * 64 + 255) / 256, 256, 0, stream>>>(rowPtr, csr_src, csr_w,
                                                          (const float2*)buf1, dinv,
                                                          (const float2*)b1,
                                                          (float2*)buf2, N);

    // layer 2: H3 = relu_out@W2 ; agg+self+bias+l2norm -> out
    gemm_k128<NC><<<dim3((N + 15) / 16, NC / 64), 256, 0, stream>>>(buf2, W2, buf1, N);
    agg_gather2<<<(N * 64 + 255) / 256, 256, 0, stream>>>(rowPtr, csr_src, csr_w,
                                                          buf1, dinv, b2, out, N);
}

// Round 3
// 311.566 us; speedup vs baseline: 7.2663x; 1.3489x over previous
//
#include <hip/hip_runtime.h>

#define NF 128   // in/hidden features
#define NC 64    // classes

// ---- degree (weighted, fp32) + in-edge count (int) per destination ----
__global__ __launch_bounds__(256) void deg_count_kernel(const int* __restrict__ col,
                                                        const float* __restrict__ ew,
                                                        float* __restrict__ deg,
                                                        int* __restrict__ cnt, int E) {
    int e = blockIdx.x * 256 + threadIdx.x;
    if (e < E) {
        int c = col[e];
        unsafeAtomicAdd(&deg[c], ew[e]);
        atomicAdd(&cnt[c], 1);
    }
}

// ---- dinv = rsqrt(deg + 1)  (self-loop weight 1.0 folded in) ----
__global__ __launch_bounds__(256) void dinv_kernel(const float* __restrict__ deg,
                                                   float* __restrict__ dinv, int N) {
    int n = blockIdx.x * 256 + threadIdx.x;
    if (n < N) {
        float d = deg[n] + 1.0f;
        dinv[n] = d > 0.0f ? rsqrtf(d) : 0.0f;
    }
}

// ---- exclusive scan of cnt[N] -> rowPtr[N+1], 1024 elems/block ----
__global__ __launch_bounds__(256) void scan_blocks(const int* __restrict__ cnt,
                                                   int* __restrict__ excl,
                                                   int* __restrict__ bsum, int N) {
    __shared__ int sh[256];
    int t = threadIdx.x;
    int base = blockIdx.x * 1024 + t * 4;
    int v0 = base + 0 < N ? cnt[base + 0] : 0;
    int v1 = base + 1 < N ? cnt[base + 1] : 0;
    int v2 = base + 2 < N ? cnt[base + 2] : 0;
    int v3 = base + 3 < N ? cnt[base + 3] : 0;
    int s = v0 + v1 + v2 + v3;
    sh[t] = s;
    __syncthreads();
    for (int off = 1; off < 256; off <<= 1) {
        int x = (t >= off) ? sh[t - off] : 0;
        __syncthreads();
        sh[t] += x;
        __syncthreads();
    }
    int incl = sh[t];
    int exclT = incl - s;
    if (t == 255) bsum[blockIdx.x] = incl;
    if (base + 0 < N) excl[base + 0] = exclT;
    if (base + 1 < N) excl[base + 1] = exclT + v0;
    if (base + 2 < N) excl[base + 2] = exclT + v0 + v1;
    if (base + 3 < N) excl[base + 3] = exclT + v0 + v1 + v2;
}

__global__ void scan_sums(int* __restrict__ bsum, int nb) {
    int run = 0;
    for (int i = 0; i < nb; ++i) { int v = bsum[i]; bsum[i] = run; run += v; }
    bsum[nb] = run;
}

__global__ __launch_bounds__(256) void scan_add(int* __restrict__ excl,
                                                const int* __restrict__ bsum,
                                                int N, int nb) {
    int i = blockIdx.x * 256 + threadIdx.x;
    if (i < N) excl[i] += bsum[i >> 10];
    if (i == 0) excl[N] = bsum[nb];
}

// ---- scatter edges into CSR pairs (src, normalized weight), indexed by col ----
__global__ __launch_bounds__(256) void scatter_kernel(const int* __restrict__ row,
                                                      const int* __restrict__ col,
                                                      const float* __restrict__ ew,
                                                      const float* __restrict__ dinv,
                                                      const int* __restrict__ rowPtr,
                                                      int* __restrict__ cursor,
                                                      int2* __restrict__ csr, int E) {
    int e = blockIdx.x * 256 + threadIdx.x;
    if (e >= E) return;
    int r = row[e], c = col[e];
    int pos = atomicAdd(&cursor[c], 1);
    float wn = dinv[r] * ew[e] * dinv[c];
    csr[rowPtr[c] + pos] = make_int2(r, __float_as_int(wn));
}

// ---- H[N x MOUT] = X[N x 128] @ W[128 x MOUT]; BM=128, BK=64, 256 thr, 8x(4*NCH) ----
template<int MOUT>
__global__ __launch_bounds__(256) void gemm_tile(const float* __restrict__ X,
                                                 const float* __restrict__ W,
                                                 float* __restrict__ H, int N) {
    constexpr int NCH = MOUT / 64;      // col halves: 2 (MOUT=128) or 1 (MOUT=64)
    __shared__ float Xs[64][128];
    __shared__ float Wsh[64][MOUT];
    const int bm0 = blockIdx.x * 128;
    const int tid = threadIdx.x;
    const int tx = tid & 15, ty = tid >> 4;
    float acc[2][NCH][4][4] = {};
    for (int kc = 0; kc < 2; ++kc) {
        // stage X chunk transposed: row r = tid>>1, k-half = (tid&1)*32
        {
            int r = tid >> 1;
            int k0 = (tid & 1) * 32;
            int node = min(bm0 + r, N - 1);
            const float4* src = (const float4*)(X + (size_t)node * 128 + kc * 64 + k0);
#pragma unroll
            for (int j4 = 0; j4 < 8; ++j4) {
                float4 v = src[j4];
                int k = k0 + j4 * 4;
                Xs[k + 0][r] = v.x;
                Xs[k + 1][r] = v.y;
                Xs[k + 2][r] = v.z;
                Xs[k + 3][r] = v.w;
            }
        }
        // stage W chunk (rows kc*64..+63 are contiguous at full MOUT width)
        {
            const float4* src = (const float4*)(W + (size_t)kc * 64 * MOUT);
            float4* dst = (float4*)&Wsh[0][0];
#pragma unroll
            for (int i = tid; i < 64 * MOUT / 4; i += 256) dst[i] = src[i];
        }
        __syncthreads();
#pragma unroll 4
        for (int k = 0; k < 64; ++k) {
            float4 xa = *(const float4*)&Xs[k][tx * 4];
            float4 xb = *(const float4*)&Xs[k][64 + tx * 4];
            float xv[2][4] = {{xa.x, xa.y, xa.z, xa.w}, {xb.x, xb.y, xb.z, xb.w}};
            float wv[NCH][4];
#pragma unroll
            for (int c = 0; c < NCH; ++c) {
                float4 w4 = *(const float4*)&Wsh[k][c * 64 + ty * 4];
                wv[c][0] = w4.x; wv[c][1] = w4.y; wv[c][2] = w4.z; wv[c][3] = w4.w;
            }
#pragma unroll
            for (int h = 0; h < 2; ++h)
#pragma unroll
                for (int c = 0; c < NCH; ++c)
#pragma unroll
                    for (int i = 0; i < 4; ++i)
#pragma unroll
                        for (int j = 0; j < 4; ++j)
                            acc[h][c][i][j] = fmaf(xv[h][i], wv[c][j], acc[h][c][i][j]);
        }
        __syncthreads();
    }
#pragma unroll
    for (int h = 0; h < 2; ++h)
#pragma unroll
        for (int i = 0; i < 4; ++i) {
            int n = bm0 + h * 64 + tx * 4 + i;
            if (n < N) {
#pragma unroll
                for (int c = 0; c < NCH; ++c) {
                    float4 o = make_float4(acc[h][c][i][0], acc[h][c][i][1],
                                           acc[h][c][i][2], acc[h][c][i][3]);
                    *(float4*)&H[(size_t)n * MOUT + c * 64 + ty * 4] = o;
                }
            }
        }
}

// ---- layer 1 gather-aggregate + self + bias + relu. One wave per node, lane=float2 ----
__global__ __launch_bounds__(256) void agg_gather1(const int* __restrict__ rowPtr,
                                                   const int2* __restrict__ csr,
                                                   const float2* __restrict__ H2,
                                                   const float* __restrict__ dinv,
                                                   const float2* __restrict__ b2,
                                                   float2* __restrict__ out2, int N) {
    int wave = (blockIdx.x * 256 + threadIdx.x) >> 6;
    int lane = threadIdx.x & 63;
    if (wave >= N) return;
    const int n = wave;
    const int F2 = NF / 2;
    float s = dinv[n]; s *= s;
    float2 h = H2[(size_t)n * F2 + lane];
    float accx = s * h.x, accy = s * h.y;
    int beg = rowPtr[n], end = rowPtr[n + 1];
    for (int base = beg; base < end; base += 64) {
        int i = base + lane;
        int2 p = i < end ? csr[i] : make_int2(0, 0);
        int m = min(end - base, 64);
        for (int j = 0; j < m; ++j) {
            int   r = __shfl(p.x, j, 64);
            float w = __int_as_float(__shfl(p.y, j, 64));
            float2 v = H2[(size_t)r * F2 + lane];
            accx += w * v.x;
            accy += w * v.y;
        }
    }
    float2 bb = b2[lane];
    float2 o;
    o.x = fmaxf(accx + bb.x, 0.f);
    o.y = fmaxf(accy + bb.y, 0.f);
    out2[(size_t)n * F2 + lane] = o;
}

// ---- layer 2 gather-aggregate + self + bias + L2 normalize. One wave per node ----
__global__ __launch_bounds__(256) void agg_gather2(const int* __restrict__ rowPtr,
                                                   const int2* __restrict__ csr,
                                                   const float* __restrict__ H,
                                                   const float* __restrict__ dinv,
                                                   const float* __restrict__ b,
                                                   float* __restrict__ out, int N) {
    int wave = (blockIdx.x * 256 + threadIdx.x) >> 6;
    int lane = threadIdx.x & 63;
    if (wave >= N) return;
    const int n = wave;
    float s = dinv[n]; s *= s;
    float acc = s * H[(size_t)n * NC + lane];
    int beg = rowPtr[n], end = rowPtr[n + 1];
    for (int base = beg; base < end; base += 64) {
        int i = base + lane;
        int2 p = i < end ? csr[i] : make_int2(0, 0);
        int m = min(end - base, 64);
        for (int j = 0; j < m; ++j) {
            int   r = __shfl(p.x, j, 64);
            float w = __int_as_float(__shfl(p.y, j, 64));
            acc += w * H[(size_t)r * NC + lane];
        }
    }
    acc += b[lane];
    float ss = acc * acc;
#pragma unroll
    for (int off = 32; off; off >>= 1) ss += __shfl_xor(ss, off, 64);
    float scale = 1.0f / fmaxf(sqrtf(ss), 1e-12f);
    out[(size_t)n * NC + lane] = acc * scale;
}

extern "C" void kernel_launch(void* const* d_in, const int* in_sizes, int n_in,
                              void* d_out, int out_size, void* d_ws, size_t ws_size,
                              hipStream_t stream) {
    const float* x  = (const float*)d_in[0];
    const int*   ei = (const int*)d_in[1];
    const float* ew = (const float*)d_in[2];
    const float* W1 = (const float*)d_in[3];
    const float* b1 = (const float*)d_in[4];
    const float* W2 = (const float*)d_in[5];
    const float* b2 = (const float*)d_in[6];
    float* out = (float*)d_out;
    const int N = in_sizes[0] / NF;
    const int E = in_sizes[2];
    const int* row = ei;
    const int* col = ei + E;
    const int NB = (N + 1023) / 1024;

    char* ws = (char*)d_ws;
    size_t off = 0;
    auto take = [&](size_t bytes) {
        char* p = ws + off;
        off = (off + bytes + 255) & ~(size_t)255;
        return p;
    };
    float* deg    = (float*)take((size_t)N * 4);
    float* dinv   = (float*)take((size_t)N * 4);
    int*   cnt    = (int*)  take((size_t)N * 4);
    int*   rowPtr = (int*)  take((size_t)(N + 1) * 4);
    int*   cursor = (int*)  take((size_t)N * 4);
    int*   bsum   = (int*)  take((size_t)(NB + 1) * 4);
    int2*  csr    = (int2*) take((size_t)E * 8);
    float* buf1   = (float*)take((size_t)N * NF * 4);  // H1, later H3 (N*NC)
    float* buf2   = (float*)take((size_t)N * NF * 4);  // relu output

    hipMemsetAsync(deg, 0, (size_t)N * 4, stream);
    hipMemsetAsync(cnt, 0, (size_t)N * 4, stream);
    hipMemsetAsync(cursor, 0, (size_t)N * 4, stream);

    deg_count_kernel<<<(E + 255) / 256, 256, 0, stream>>>(col, ew, deg, cnt, E);
    dinv_kernel<<<(N + 255) / 256, 256, 0, stream>>>(deg, dinv, N);

    scan_blocks<<<NB, 256, 0, stream>>>(cnt, rowPtr, bsum, N);
    scan_sums<<<1, 1, 0, stream>>>(bsum, NB);
    scan_add<<<(N + 255) / 256, 256, 0, stream>>>(rowPtr, bsum, N, NB);
    scatter_kernel<<<(E + 255) / 256, 256, 0, stream>>>(row, col, ew, dinv, rowPtr,
                                                        cursor, csr, E);

    // layer 1: H1 = X@W1 ; agg+self+bias+relu -> buf2
    gemm_tile<NF><<<(N + 127) / 128, 256, 0, stream>>>(x, W1, buf1, N);
    agg_gather1<<<(N * 64 + 255) / 256, 256, 0, stream>>>(rowPtr, csr,
                                                          (const float2*)buf1, dinv,
                                                          (const float2*)b1,
                                                          (float2*)buf2, N);

    // layer 2: H3 = relu_out@W2 ; agg+self+bias+l2norm -> out
    gemm_tile<NC><<<(N + 127) / 128, 256, 0, stream>>>(buf2, W2, buf1, N);
    agg_gather2<<<(N * 64 + 255) / 256, 256, 0, stream>>>(rowPtr, csr,
                                                          buf1, dinv, b2, out, N);
}

// Round 4
// 271.759 us; speedup vs baseline: 8.3307x; 1.1465x over previous
//
#include <hip/hip_runtime.h>

#define NF 128   // in/hidden features
#define NC 64    // classes

__device__ __forceinline__ unsigned f2bf(float f) {   // fp32 -> bf16 (RTN)
    unsigned u = __float_as_uint(f);
    return (u + 0x7FFFu + ((u >> 16) & 1u)) >> 16;
}
__device__ __forceinline__ float bf2f(unsigned h) { return __uint_as_float(h << 16); }

// ---- fused: count-role blocks (cnt[col]++) + gemm-role blocks (H1 = X@W1, bf16 out) ----
__global__ __launch_bounds__(256) void gemm1_cnt_fused(const float* __restrict__ X,
                                                       const float* __restrict__ W,
                                                       unsigned short* __restrict__ H,  // [N][128] bf16
                                                       const int* __restrict__ col,
                                                       int* __restrict__ cnt,
                                                       int N, int E, int CB) {
    if ((int)blockIdx.x < CB) {
        int stride = CB * 256;
        for (int e = blockIdx.x * 256 + threadIdx.x; e < E; e += stride)
            atomicAdd(&cnt[col[e]], 1);
        return;
    }
    const int bm0 = (blockIdx.x - CB) * 128;
    __shared__ float Xs[64][128];
    __shared__ float Wsh[64][128];
    const int tid = threadIdx.x;
    const int tx = tid & 15, ty = tid >> 4;
    float acc[2][2][4][4] = {};
    for (int kc = 0; kc < 2; ++kc) {
        {
            int r = tid >> 1;
            int k0 = (tid & 1) * 32;
            int node = min(bm0 + r, N - 1);
            const float4* src = (const float4*)(X + (size_t)node * 128 + kc * 64 + k0);
#pragma unroll
            for (int j4 = 0; j4 < 8; ++j4) {
                float4 v = src[j4];
                int k = k0 + j4 * 4;
                Xs[k + 0][r] = v.x;
                Xs[k + 1][r] = v.y;
                Xs[k + 2][r] = v.z;
                Xs[k + 3][r] = v.w;
            }
        }
        {
            const float4* src = (const float4*)(W + (size_t)kc * 64 * 128);
            float4* dst = (float4*)&Wsh[0][0];
#pragma unroll
            for (int i = tid; i < 64 * 128 / 4; i += 256) dst[i] = src[i];
        }
        __syncthreads();
#pragma unroll 4
        for (int k = 0; k < 64; ++k) {
            float4 xa = *(const float4*)&Xs[k][tx * 4];
            float4 xb = *(const float4*)&Xs[k][64 + tx * 4];
            float xv[2][4] = {{xa.x, xa.y, xa.z, xa.w}, {xb.x, xb.y, xb.z, xb.w}};
            float wv[2][4];
#pragma unroll
            for (int c = 0; c < 2; ++c) {
                float4 w4 = *(const float4*)&Wsh[k][c * 64 + ty * 4];
                wv[c][0] = w4.x; wv[c][1] = w4.y; wv[c][2] = w4.z; wv[c][3] = w4.w;
            }
#pragma unroll
            for (int h = 0; h < 2; ++h)
#pragma unroll
                for (int c = 0; c < 2; ++c)
#pragma unroll
                    for (int i = 0; i < 4; ++i)
#pragma unroll
                        for (int j = 0; j < 4; ++j)
                            acc[h][c][i][j] = fmaf(xv[h][i], wv[c][j], acc[h][c][i][j]);
        }
        __syncthreads();
    }
#pragma unroll
    for (int h = 0; h < 2; ++h)
#pragma unroll
        for (int i = 0; i < 4; ++i) {
            int n = bm0 + h * 64 + tx * 4 + i;
            if (n < N) {
#pragma unroll
                for (int c = 0; c < 2; ++c) {
                    ushort4 o;
                    o.x = (unsigned short)f2bf(acc[h][c][i][0]);
                    o.y = (unsigned short)f2bf(acc[h][c][i][1]);
                    o.z = (unsigned short)f2bf(acc[h][c][i][2]);
                    o.w = (unsigned short)f2bf(acc[h][c][i][3]);
                    *(ushort4*)&H[(size_t)n * 128 + c * 64 + ty * 4] = o;
                }
            }
        }
}

// ---- exclusive scan of cnt[N] -> rowPtr[N+1], 1024 elems/block ----
__global__ __launch_bounds__(256) void scan_blocks(const int* __restrict__ cnt,
                                                   int* __restrict__ excl,
                                                   int* __restrict__ bsum, int N) {
    __shared__ int sh[256];
    int t = threadIdx.x;
    int base = blockIdx.x * 1024 + t * 4;
    int v0 = base + 0 < N ? cnt[base + 0] : 0;
    int v1 = base + 1 < N ? cnt[base + 1] : 0;
    int v2 = base + 2 < N ? cnt[base + 2] : 0;
    int v3 = base + 3 < N ? cnt[base + 3] : 0;
    int s = v0 + v1 + v2 + v3;
    sh[t] = s;
    __syncthreads();
    for (int off = 1; off < 256; off <<= 1) {
        int x = (t >= off) ? sh[t - off] : 0;
        __syncthreads();
        sh[t] += x;
        __syncthreads();
    }
    int incl = sh[t];
    int exclT = incl - s;
    if (t == 255) bsum[blockIdx.x] = incl;
    if (base + 0 < N) excl[base + 0] = exclT;
    if (base + 1 < N) excl[base + 1] = exclT + v0;
    if (base + 2 < N) excl[base + 2] = exclT + v0 + v1;
    if (base + 3 < N) excl[base + 3] = exclT + v0 + v1 + v2;
}

__global__ void scan_sums(int* __restrict__ bsum, int nb) {
    int run = 0;
    for (int i = 0; i < nb; ++i) { int v = bsum[i]; bsum[i] = run; run += v; }
    bsum[nb] = run;
}

__global__ __launch_bounds__(256) void scan_add(int* __restrict__ excl,
                                                const int* __restrict__ bsum,
                                                int N, int nb) {
    int i = blockIdx.x * 256 + threadIdx.x;
    if (i < N) excl[i] += bsum[i >> 10];
    if (i == 0) excl[N] = bsum[nb];
}

// ---- scatter edges into CSR pairs (src, RAW ew bits), indexed by col ----
__global__ __launch_bounds__(256) void scatter_kernel(const int* __restrict__ row,
                                                      const int* __restrict__ col,
                                                      const float* __restrict__ ew,
                                                      const int* __restrict__ rowPtr,
                                                      int* __restrict__ cursor,
                                                      int2* __restrict__ csr, int E) {
    int e = blockIdx.x * 256 + threadIdx.x;
    if (e >= E) return;
    int r = row[e], c = col[e];
    int pos = atomicAdd(&cursor[c], 1);
    csr[rowPtr[c] + pos] = make_int2(r, __float_as_int(ew[e]));
}

// ---- deg from CSR segment sum; dinv = rsqrt(deg + 1). One wave per node ----
__global__ __launch_bounds__(256) void deg_dinv_kernel(const int* __restrict__ rowPtr,
                                                       const int2* __restrict__ csr,
                                                       float* __restrict__ dinv, int N) {
    int n = (blockIdx.x * 256 + threadIdx.x) >> 6;
    int lane = threadIdx.x & 63;
    if (n >= N) return;
    int beg = rowPtr[n], end = rowPtr[n + 1];
    float s = 0.f;
    for (int i = beg + lane; i < end; i += 64) s += __int_as_float(csr[i].y);
#pragma unroll
    for (int off = 32; off; off >>= 1) s += __shfl_xor(s, off, 64);
    if (lane == 0) dinv[n] = rsqrtf(s + 1.0f);
}

// ---- normalize csr weights in place: w = dinv[src]*ew*dinv[dst]. One wave per node ----
__global__ __launch_bounds__(256) void norm_csr_kernel(const int* __restrict__ rowPtr,
                                                       int2* __restrict__ csr,
                                                       const float* __restrict__ dinv, int N) {
    int n = (blockIdx.x * 256 + threadIdx.x) >> 6;
    int lane = threadIdx.x & 63;
    if (n >= N) return;
    float dn = dinv[n];
    int beg = rowPtr[n], end = rowPtr[n + 1];
    int* wfield = (int*)csr;
    for (int i = beg + lane; i < end; i += 64) {
        int2 p = csr[i];
        float w = __int_as_float(p.y) * dinv[p.x] * dn;
        wfield[2 * i + 1] = __float_as_int(w);
    }
}

// ---- layer 1 gather (bf16 H1) + self + bias + relu. One wave per node, lane=2 feats ----
__global__ __launch_bounds__(256) void agg_gather1(const int* __restrict__ rowPtr,
                                                   const int2* __restrict__ csr,
                                                   const unsigned* __restrict__ H1u,  // [N][64] bf16x2
                                                   const float* __restrict__ dinv,
                                                   const float2* __restrict__ b2,
                                                   float2* __restrict__ out2, int N) {
    int n = (blockIdx.x * 256 + threadIdx.x) >> 6;
    int lane = threadIdx.x & 63;
    if (n >= N) return;
    float s = dinv[n]; s *= s;
    unsigned hv = H1u[(size_t)n * 64 + lane];
    float accx = s * bf2f(hv & 0xffffu);
    float accy = s * bf2f(hv >> 16);
    int beg = rowPtr[n], end = rowPtr[n + 1];
    for (int base = beg; base < end; base += 64) {
        int i = base + lane;
        int2 p = i < end ? csr[i] : make_int2(0, 0);
        int m = min(end - base, 64);
        for (int j = 0; j < m; ++j) {
            int   r = __shfl(p.x, j, 64);
            float w = __int_as_float(__shfl(p.y, j, 64));
            unsigned v = H1u[(size_t)r * 64 + lane];
            accx += w * bf2f(v & 0xffffu);
            accy += w * bf2f(v >> 16);
        }
    }
    float2 bb = b2[lane];
    float2 o;
    o.x = fmaxf(accx + bb.x, 0.f);
    o.y = fmaxf(accy + bb.y, 0.f);
    out2[(size_t)n * 64 + lane] = o;
}

// ---- H[N x 64] = X[N x 128] @ W[128 x 64] fp32 ----
__global__ __launch_bounds__(256) void gemm_tile64(const float* __restrict__ X,
                                                   const float* __restrict__ W,
                                                   float* __restrict__ H, int N) {
    __shared__ float Xs[64][128];
    __shared__ float Wsh[64][64];
    const int bm0 = blockIdx.x * 128;
    const int tid = threadIdx.x;
    const int tx = tid & 15, ty = tid >> 4;
    float acc[2][4][4] = {};
    for (int kc = 0; kc < 2; ++kc) {
        {
            int r = tid >> 1;
            int k0 = (tid & 1) * 32;
            int node = min(bm0 + r, N - 1);
            const float4* src = (const float4*)(X + (size_t)node * 128 + kc * 64 + k0);
#pragma unroll
            for (int j4 = 0; j4 < 8; ++j4) {
                float4 v = src[j4];
                int k = k0 + j4 * 4;
                Xs[k + 0][r] = v.x;
                Xs[k + 1][r] = v.y;
                Xs[k + 2][r] = v.z;
                Xs[k + 3][r] = v.w;
            }
        }
        {
            const float4* src = (const float4*)(W + (size_t)kc * 64 * 64);
            float4* dst = (float4*)&Wsh[0][0];
#pragma unroll
            for (int i = tid; i < 64 * 64 / 4; i += 256) dst[i] = src[i];
        }
        __syncthreads();
#pragma unroll 4
        for (int k = 0; k < 64; ++k) {
            float4 xa = *(const float4*)&Xs[k][tx * 4];
            float4 xb = *(const float4*)&Xs[k][64 + tx * 4];
            float xv[2][4] = {{xa.x, xa.y, xa.z, xa.w}, {xb.x, xb.y, xb.z, xb.w}};
            float4 w4 = *(const float4*)&Wsh[k][ty * 4];
            float wv[4] = {w4.x, w4.y, w4.z, w4.w};
#pragma unroll
            for (int h = 0; h < 2; ++h)
#pragma unroll
                for (int i = 0; i < 4; ++i)
#pragma unroll
                    for (int j = 0; j < 4; ++j)
                        acc[h][i][j] = fmaf(xv[h][i], wv[j], acc[h][i][j]);
        }
        __syncthreads();
    }
#pragma unroll
    for (int h = 0; h < 2; ++h)
#pragma unroll
        for (int i = 0; i < 4; ++i) {
            int n = bm0 + h * 64 + tx * 4 + i;
            if (n < N) {
                float4 o = make_float4(acc[h][i][0], acc[h][i][1], acc[h][i][2], acc[h][i][3]);
                *(float4*)&H[(size_t)n * 64 + ty * 4] = o;
            }
        }
}

// ---- layer 2 gather + self + bias + L2 normalize. One wave per node ----
__global__ __launch_bounds__(256) void agg_gather2(const int* __restrict__ rowPtr,
                                                   const int2* __restrict__ csr,
                                                   const float* __restrict__ H,
                                                   const float* __restrict__ dinv,
                                                   const float* __restrict__ b,
                                                   float* __restrict__ out, int N) {
    int n = (blockIdx.x * 256 + threadIdx.x) >> 6;
    int lane = threadIdx.x & 63;
    if (n >= N) return;
    float s = dinv[n]; s *= s;
    float acc = s * H[(size_t)n * NC + lane];
    int beg = rowPtr[n], end = rowPtr[n + 1];
    for (int base = beg; base < end; base += 64) {
        int i = base + lane;
        int2 p = i < end ? csr[i] : make_int2(0, 0);
        int m = min(end - base, 64);
        for (int j = 0; j < m; ++j) {
            int   r = __shfl(p.x, j, 64);
            float w = __int_as_float(__shfl(p.y, j, 64));
            acc += w * H[(size_t)r * NC + lane];
        }
    }
    acc += b[lane];
    float ss = acc * acc;
#pragma unroll
    for (int off = 32; off; off >>= 1) ss += __shfl_xor(ss, off, 64);
    float scale = 1.0f / fmaxf(sqrtf(ss), 1e-12f);
    out[(size_t)n * NC + lane] = acc * scale;
}

extern "C" void kernel_launch(void* const* d_in, const int* in_sizes, int n_in,
                              void* d_out, int out_size, void* d_ws, size_t ws_size,
                              hipStream_t stream) {
    const float* x  = (const float*)d_in[0];
    const int*   ei = (const int*)d_in[1];
    const float* ew = (const float*)d_in[2];
    const float* W1 = (const float*)d_in[3];
    const float* b1 = (const float*)d_in[4];
    const float* W2 = (const float*)d_in[5];
    const float* b2 = (const float*)d_in[6];
    float* out = (float*)d_out;
    const int N = in_sizes[0] / NF;
    const int E = in_sizes[2];
    const int* row = ei;
    const int* col = ei + E;
    const int NB = (N + 1023) / 1024;

    char* ws = (char*)d_ws;
    size_t off = 0;
    auto take = [&](size_t bytes) {
        char* p = ws + off;
        off = (off + bytes + 255) & ~(size_t)255;
        return p;
    };
    float* dinv   = (float*)take((size_t)N * 4);
    int*   cnt    = (int*)  take((size_t)N * 4);
    int*   rowPtr = (int*)  take((size_t)(N + 1) * 4);
    int*   cursor = (int*)  take((size_t)N * 4);
    int*   bsum   = (int*)  take((size_t)(NB + 1) * 4);
    int2*  csr    = (int2*) take((size_t)E * 8);
    unsigned short* H1 = (unsigned short*)take((size_t)N * NF * 2);  // bf16
    float* buf2   = (float*)take((size_t)N * NF * 4);  // relu output (fp32)
    float* h3     = (float*)take((size_t)N * NC * 4);  // layer-2 gemm out (fp32)

    hipMemsetAsync(cnt, 0, (size_t)N * 4, stream);
    hipMemsetAsync(cursor, 0, (size_t)N * 4, stream);

    // fused: edge counting (atomic, HBM-write-bound) || GEMM1 (VALU-bound)
    const int CB = 256;
    const int GB = (N + 127) / 128;
    gemm1_cnt_fused<<<CB + GB, 256, 0, stream>>>(x, W1, H1, col, cnt, N, E, CB);

    // CSR build
    scan_blocks<<<NB, 256, 0, stream>>>(cnt, rowPtr, bsum, N);
    scan_sums<<<1, 1, 0, stream>>>(bsum, NB);
    scan_add<<<(N + 255) / 256, 256, 0, stream>>>(rowPtr, bsum, N, NB);
    scatter_kernel<<<(E + 255) / 256, 256, 0, stream>>>(row, col, ew, rowPtr, cursor, csr, E);

    // degree -> dinv -> normalized weights (no fp32 atomics anywhere)
    deg_dinv_kernel<<<(N * 64 + 255) / 256, 256, 0, stream>>>(rowPtr, csr, dinv, N);
    norm_csr_kernel<<<(N * 64 + 255) / 256, 256, 0, stream>>>(rowPtr, csr, dinv, N);

    // layer 1 aggregation (bf16 gathers) + bias + relu
    agg_gather1<<<(N * 64 + 255) / 256, 256, 0, stream>>>(rowPtr, csr, (const unsigned*)H1,
                                                          dinv, (const float2*)b1,
                                                          (float2*)buf2, N);

    // layer 2: GEMM (fp32) ; gather + bias + l2norm
    gemm_tile64<<<(N + 127) / 128, 256, 0, stream>>>(buf2, W2, h3, N);
    agg_gather2<<<(N * 64 + 255) / 256, 256, 0, stream>>>(rowPtr, csr, h3, dinv, b2, out, N);
}

// Round 5
// 218.849 us; speedup vs baseline: 10.3447x; 1.2418x over previous
//
#include <hip/hip_runtime.h>

#define NF 128   // in/hidden features
#define NC 64    // classes

__device__ __forceinline__ unsigned f2bf(float f) {   // fp32 -> bf16 (RTN)
    unsigned u = __float_as_uint(f);
    return (u + 0x7FFFu + ((u >> 16) & 1u)) >> 16;
}
__device__ __forceinline__ float bf2f(unsigned h) { return __uint_as_float(h << 16); }

// ---- fused: count-role blocks (eoff[e]=cnt[col]++) + gemm-role (H1 = X@W1, bf16 out) ----
__global__ __launch_bounds__(256) void gemm1_cnt_fused(const float* __restrict__ X,
                                                       const float* __restrict__ W,
                                                       unsigned short* __restrict__ H,  // [N][128] bf16
                                                       const int* __restrict__ col,
                                                       int* __restrict__ cnt,
                                                       int* __restrict__ eoff,
                                                       int N, int E, int CB) {
    __shared__ float Xs[32][128];
    __shared__ float Wsh[32][128];
    if ((int)blockIdx.x < CB) {
        int stride = CB * 256;
        for (int e = blockIdx.x * 256 + threadIdx.x; e < E; e += stride)
            eoff[e] = atomicAdd(&cnt[col[e]], 1);
        return;
    }
    const int bm0 = (blockIdx.x - CB) * 128;
    const int tid = threadIdx.x;
    const int tx = tid & 15, ty = tid >> 4;
    float acc[2][2][4][4] = {};
    for (int kc = 0; kc < 4; ++kc) {
        {
            int r = tid >> 1;
            int k0 = (tid & 1) * 16;
            int node = min(bm0 + r, N - 1);
            const float4* src = (const float4*)(X + (size_t)node * 128 + kc * 32 + k0);
#pragma unroll
            for (int j4 = 0; j4 < 4; ++j4) {
                float4 v = src[j4];
                int k = k0 + j4 * 4;
                Xs[k + 0][r] = v.x;
                Xs[k + 1][r] = v.y;
                Xs[k + 2][r] = v.z;
                Xs[k + 3][r] = v.w;
            }
        }
        {
            const float4* src = (const float4*)(W + (size_t)kc * 32 * 128);
            float4* dst = (float4*)&Wsh[0][0];
#pragma unroll
            for (int i = tid; i < 32 * 128 / 4; i += 256) dst[i] = src[i];
        }
        __syncthreads();
#pragma unroll 4
        for (int k = 0; k < 32; ++k) {
            float4 xa = *(const float4*)&Xs[k][tx * 4];
            float4 xb = *(const float4*)&Xs[k][64 + tx * 4];
            float xv[2][4] = {{xa.x, xa.y, xa.z, xa.w}, {xb.x, xb.y, xb.z, xb.w}};
            float wv[2][4];
#pragma unroll
            for (int c = 0; c < 2; ++c) {
                float4 w4 = *(const float4*)&Wsh[k][c * 64 + ty * 4];
                wv[c][0] = w4.x; wv[c][1] = w4.y; wv[c][2] = w4.z; wv[c][3] = w4.w;
            }
#pragma unroll
            for (int h = 0; h < 2; ++h)
#pragma unroll
                for (int c = 0; c < 2; ++c)
#pragma unroll
                    for (int i = 0; i < 4; ++i)
#pragma unroll
                        for (int j = 0; j < 4; ++j)
                            acc[h][c][i][j] = fmaf(xv[h][i], wv[c][j], acc[h][c][i][j]);
        }
        __syncthreads();
    }
#pragma unroll
    for (int h = 0; h < 2; ++h)
#pragma unroll
        for (int i = 0; i < 4; ++i) {
            int n = bm0 + h * 64 + tx * 4 + i;
            if (n < N) {
#pragma unroll
                for (int c = 0; c < 2; ++c) {
                    ushort4 o;
                    o.x = (unsigned short)f2bf(acc[h][c][i][0]);
                    o.y = (unsigned short)f2bf(acc[h][c][i][1]);
                    o.z = (unsigned short)f2bf(acc[h][c][i][2]);
                    o.w = (unsigned short)f2bf(acc[h][c][i][3]);
                    *(ushort4*)&H[(size_t)n * 128 + c * 64 + ty * 4] = o;
                }
            }
        }
}

// ---- exclusive scan of cnt[N] -> rowPtr[N+1], 1024 elems/block ----
__global__ __launch_bounds__(256) void scan_blocks(const int* __restrict__ cnt,
                                                   int* __restrict__ excl,
                                                   int* __restrict__ bsum, int N) {
    __shared__ int sh[256];
    int t = threadIdx.x;
    int base = blockIdx.x * 1024 + t * 4;
    int v0 = base + 0 < N ? cnt[base + 0] : 0;
    int v1 = base + 1 < N ? cnt[base + 1] : 0;
    int v2 = base + 2 < N ? cnt[base + 2] : 0;
    int v3 = base + 3 < N ? cnt[base + 3] : 0;
    int s = v0 + v1 + v2 + v3;
    sh[t] = s;
    __syncthreads();
    for (int off = 1; off < 256; off <<= 1) {
        int x = (t >= off) ? sh[t - off] : 0;
        __syncthreads();
        sh[t] += x;
        __syncthreads();
    }
    int incl = sh[t];
    int exclT = incl - s;
    if (t == 255) bsum[blockIdx.x] = incl;
    if (base + 0 < N) excl[base + 0] = exclT;
    if (base + 1 < N) excl[base + 1] = exclT + v0;
    if (base + 2 < N) excl[base + 2] = exclT + v0 + v1;
    if (base + 3 < N) excl[base + 3] = exclT + v0 + v1 + v2;
}

__global__ void scan_sums(int* __restrict__ bsum, int nb) {
    int run = 0;
    for (int i = 0; i < nb; ++i) { int v = bsum[i]; bsum[i] = run; run += v; }
    bsum[nb] = run;
}

__global__ __launch_bounds__(256) void scan_add(int* __restrict__ excl,
                                                const int* __restrict__ bsum,
                                                int N, int nb) {
    int i = blockIdx.x * 256 + threadIdx.x;
    if (i < N) excl[i] += bsum[i >> 10];
    if (i == 0) excl[N] = bsum[nb];
}

// ---- scatter edges into CSR pairs (src, RAW ew bits) — no atomics ----
__global__ __launch_bounds__(256) void scatter_kernel(const int* __restrict__ row,
                                                      const int* __restrict__ col,
                                                      const float* __restrict__ ew,
                                                      const int* __restrict__ rowPtr,
                                                      const int* __restrict__ eoff,
                                                      int2* __restrict__ csr, int E) {
    int e = blockIdx.x * 256 + threadIdx.x;
    if (e >= E) return;
    int c = col[e];
    csr[rowPtr[c] + eoff[e]] = make_int2(row[e], __float_as_int(ew[e]));
}

// ---- deg from CSR segment sum; dinv = rsqrt(deg + 1). 16 lanes per node ----
__global__ __launch_bounds__(256) void deg_dinv_kernel(const int* __restrict__ rowPtr,
                                                       const int2* __restrict__ csr,
                                                       float* __restrict__ dinv, int N) {
    int idx = blockIdx.x * 256 + threadIdx.x;
    int n = idx >> 4, l = idx & 15;
    if (n >= N) return;
    int beg = rowPtr[n], end = rowPtr[n + 1];
    float s = 0.f;
    for (int i = beg + l; i < end; i += 16) s += __int_as_float(csr[i].y);
#pragma unroll
    for (int off = 8; off; off >>= 1) s += __shfl_xor(s, off, 16);
    if (l == 0) dinv[n] = rsqrtf(s + 1.0f);
}

// ---- layer 1 gather (bf16 H1) + on-fly norm + self + bias + relu. Wave per node ----
__global__ __launch_bounds__(256) void agg_gather1(const int* __restrict__ rowPtr,
                                                   const int2* __restrict__ csr,
                                                   const unsigned* __restrict__ H1u,  // [N][64] bf16x2
                                                   const float* __restrict__ dinv,
                                                   const float2* __restrict__ b2,
                                                   float2* __restrict__ out2, int N) {
    int n = (blockIdx.x * 256 + threadIdx.x) >> 6;
    int lane = threadIdx.x & 63;
    if (n >= N) return;
    float dn = dinv[n];
    unsigned hv = H1u[(size_t)n * 64 + lane];
    float accx = 0.f, accy = 0.f;
    int beg = rowPtr[n], end = rowPtr[n + 1];
    for (int base = beg; base < end; base += 64) {
        int i = base + lane;
        int2 p = i < end ? csr[i] : make_int2(0, 0);
        float wl = __int_as_float(p.y) * dinv[p.x];   // ew * dinv[src]
        int m = min(end - base, 64);
        for (int j = 0; j < m; ++j) {
            int   r = __shfl(p.x, j, 64);
            float w = __shfl(wl, j, 64);
            unsigned v = H1u[(size_t)r * 64 + lane];
            accx += w * bf2f(v & 0xffffu);
            accy += w * bf2f(v >> 16);
        }
    }
    float2 bb = b2[lane];
    float s = dn * dn;
    float2 o;
    o.x = fmaxf(fmaf(dn, accx, s * bf2f(hv & 0xffffu)) + bb.x, 0.f);
    o.y = fmaxf(fmaf(dn, accy, s * bf2f(hv >> 16)) + bb.y, 0.f);
    out2[(size_t)n * 64 + lane] = o;
}

// ---- H[N x 64] = X[N x 128] @ W[128 x 64] fp32, BK=32 ----
__global__ __launch_bounds__(256) void gemm_tile64(const float* __restrict__ X,
                                                   const float* __restrict__ W,
                                                   float* __restrict__ H, int N) {
    __shared__ float Xs[32][128];
    __shared__ float Wsh[32][64];
    const int bm0 = blockIdx.x * 128;
    const int tid = threadIdx.x;
    const int tx = tid & 15, ty = tid >> 4;
    float acc[2][4][4] = {};
    for (int kc = 0; kc < 4; ++kc) {
        {
            int r = tid >> 1;
            int k0 = (tid & 1) * 16;
            int node = min(bm0 + r, N - 1);
            const float4* src = (const float4*)(X + (size_t)node * 128 + kc * 32 + k0);
#pragma unroll
            for (int j4 = 0; j4 < 4; ++j4) {
                float4 v = src[j4];
                int k = k0 + j4 * 4;
                Xs[k + 0][r] = v.x;
                Xs[k + 1][r] = v.y;
                Xs[k + 2][r] = v.z;
                Xs[k + 3][r] = v.w;
            }
        }
        {
            const float4* src = (const float4*)(W + (size_t)kc * 32 * 64);
            float4* dst = (float4*)&Wsh[0][0];
#pragma unroll
            for (int i = tid; i < 32 * 64 / 4; i += 256) dst[i] = src[i];
        }
        __syncthreads();
#pragma unroll 4
        for (int k = 0; k < 32; ++k) {
            float4 xa = *(const float4*)&Xs[k][tx * 4];
            float4 xb = *(const float4*)&Xs[k][64 + tx * 4];
            float xv[2][4] = {{xa.x, xa.y, xa.z, xa.w}, {xb.x, xb.y, xb.z, xb.w}};
            float4 w4 = *(const float4*)&Wsh[k][ty * 4];
            float wv[4] = {w4.x, w4.y, w4.z, w4.w};
#pragma unroll
            for (int h = 0; h < 2; ++h)
#pragma unroll
                for (int i = 0; i < 4; ++i)
#pragma unroll
                    for (int j = 0; j < 4; ++j)
                        acc[h][i][j] = fmaf(xv[h][i], wv[j], acc[h][i][j]);
        }
        __syncthreads();
    }
#pragma unroll
    for (int h = 0; h < 2; ++h)
#pragma unroll
        for (int i = 0; i < 4; ++i) {
            int n = bm0 + h * 64 + tx * 4 + i;
            if (n < N) {
                float4 o = make_float4(acc[h][i][0], acc[h][i][1], acc[h][i][2], acc[h][i][3]);
                *(float4*)&H[(size_t)n * 64 + ty * 4] = o;
            }
        }
}

// ---- layer 2 gather + on-fly norm + self + bias + L2 normalize. Wave per node ----
__global__ __launch_bounds__(256) void agg_gather2(const int* __restrict__ rowPtr,
                                                   const int2* __restrict__ csr,
                                                   const float* __restrict__ H,
                                                   const float* __restrict__ dinv,
                                                   const float* __restrict__ b,
                                                   float* __restrict__ out, int N) {
    int n = (blockIdx.x * 256 + threadIdx.x) >> 6;
    int lane = threadIdx.x & 63;
    if (n >= N) return;
    float dn = dinv[n];
    float acc = 0.f;
    int beg = rowPtr[n], end = rowPtr[n + 1];
    for (int base = beg; base < end; base += 64) {
        int i = base + lane;
        int2 p = i < end ? csr[i] : make_int2(0, 0);
        float wl = __int_as_float(p.y) * dinv[p.x];
        int m = min(end - base, 64);
        for (int j = 0; j < m; ++j) {
            int   r = __shfl(p.x, j, 64);
            float w = __shfl(wl, j, 64);
            acc += w * H[(size_t)r * NC + lane];
        }
    }
    acc = fmaf(dn, acc, dn * dn * H[(size_t)n * NC + lane]) + b[lane];
    float ss = acc * acc;
#pragma unroll
    for (int off = 32; off; off >>= 1) ss += __shfl_xor(ss, off, 64);
    float scale = 1.0f / fmaxf(sqrtf(ss), 1e-12f);
    out[(size_t)n * NC + lane] = acc * scale;
}

extern "C" void kernel_launch(void* const* d_in, const int* in_sizes, int n_in,
                              void* d_out, int out_size, void* d_ws, size_t ws_size,
                              hipStream_t stream) {
    const float* x  = (const float*)d_in[0];
    const int*   ei = (const int*)d_in[1];
    const float* ew = (const float*)d_in[2];
    const float* W1 = (const float*)d_in[3];
    const float* b1 = (const float*)d_in[4];
    const float* W2 = (const float*)d_in[5];
    const float* b2 = (const float*)d_in[6];
    float* out = (float*)d_out;
    const int N = in_sizes[0] / NF;
    const int E = in_sizes[2];
    const int* row = ei;
    const int* col = ei + E;
    const int NB = (N + 1023) / 1024;

    char* ws = (char*)d_ws;
    size_t off = 0;
    auto take = [&](size_t bytes) {
        char* p = ws + off;
        off = (off + bytes + 255) & ~(size_t)255;
        return p;
    };
    float* dinv   = (float*)take((size_t)N * 4);
    int*   cnt    = (int*)  take((size_t)N * 4);
    int*   rowPtr = (int*)  take((size_t)(N + 1) * 4);
    int*   eoff   = (int*)  take((size_t)E * 4);
    int*   bsum   = (int*)  take((size_t)(NB + 1) * 4);
    int2*  csr    = (int2*) take((size_t)E * 8);
    unsigned short* H1 = (unsigned short*)take((size_t)N * NF * 2);  // bf16
    float* buf2   = (float*)take((size_t)N * NF * 4);  // relu output (fp32)
    float* h3     = (float*)take((size_t)N * NC * 4);  // layer-2 gemm out (fp32)

    hipMemsetAsync(cnt, 0, (size_t)N * 4, stream);

    // fused: edge counting+eoff (atomic-bound) || GEMM1 (VALU/LDS-bound)
    const int CB = 256;
    const int GB = (N + 127) / 128;
    gemm1_cnt_fused<<<CB + GB, 256, 0, stream>>>(x, W1, H1, col, cnt, eoff, N, E, CB);

    // CSR build (atomic-free scatter)
    scan_blocks<<<NB, 256, 0, stream>>>(cnt, rowPtr, bsum, N);
    scan_sums<<<1, 1, 0, stream>>>(bsum, NB);
    scan_add<<<(N + 255) / 256, 256, 0, stream>>>(rowPtr, bsum, N, NB);
    scatter_kernel<<<(E + 255) / 256, 256, 0, stream>>>(row, col, ew, rowPtr, eoff, csr, E);

    // degree -> dinv (weights normalized on the fly in agg kernels)
    deg_dinv_kernel<<<(N * 16 + 255) / 256, 256, 0, stream>>>(rowPtr, csr, dinv, N);

    // layer 1 aggregation (bf16 gathers) + bias + relu
    agg_gather1<<<(N * 64 + 255) / 256, 256, 0, stream>>>(rowPtr, csr, (const unsigned*)H1,
                                                          dinv, (const float2*)b1,
                                                          (float2*)buf2, N);

    // layer 2: GEMM (fp32) ; gather + bias + l2norm
    gemm_tile64<<<(N + 127) / 128, 256, 0, stream>>>(buf2, W2, h3, N);
    agg_gather2<<<(N * 64 + 255) / 256, 256, 0, stream>>>(rowPtr, csr, h3, dinv, b2, out, N);
}

// Round 6
// 175.124 us; speedup vs baseline: 12.9276x; 1.2497x over previous
//
#include <hip/hip_runtime.h>

#define NF 128   // in/hidden features
#define NC 64    // classes

__device__ __forceinline__ unsigned f2bf(float f) {   // fp32 -> bf16 (RTN)
    unsigned u = __float_as_uint(f);
    return (u + 0x7FFFu + ((u >> 16) & 1u)) >> 16;
}
__device__ __forceinline__ float bf2f(unsigned h) { return __uint_as_float(h << 16); }

// ---- fused: count-role blocks (eoff[e]=cnt[col]++) + gemm-role (H1 = X@W1, bf16 out) ----
__global__ __launch_bounds__(256) void gemm1_cnt_fused(const float* __restrict__ X,
                                                       const float* __restrict__ W,
                                                       unsigned short* __restrict__ H,  // [N][128] bf16
                                                       const int* __restrict__ col,
                                                       int* __restrict__ cnt,
                                                       int* __restrict__ eoff,
                                                       int N, int E, int CB) {
    __shared__ float Xs[32][128];
    __shared__ float Wsh[32][128];
    if ((int)blockIdx.x < CB) {
        int stride = CB * 256;
        for (int e = blockIdx.x * 256 + threadIdx.x; e < E; e += stride)
            eoff[e] = atomicAdd(&cnt[col[e]], 1);
        return;
    }
    const int bm0 = (blockIdx.x - CB) * 128;
    const int tid = threadIdx.x;
    const int tx = tid & 15, ty = tid >> 4;
    float acc[2][2][4][4] = {};
    for (int kc = 0; kc < 4; ++kc) {
        {
            int r = tid >> 1;
            int k0 = (tid & 1) * 16;
            int node = min(bm0 + r, N - 1);
            const float4* src = (const float4*)(X + (size_t)node * 128 + kc * 32 + k0);
#pragma unroll
            for (int j4 = 0; j4 < 4; ++j4) {
                float4 v = src[j4];
                int k = k0 + j4 * 4;
                Xs[k + 0][r] = v.x;
                Xs[k + 1][r] = v.y;
                Xs[k + 2][r] = v.z;
                Xs[k + 3][r] = v.w;
            }
        }
        {
            const float4* src = (const float4*)(W + (size_t)kc * 32 * 128);
            float4* dst = (float4*)&Wsh[0][0];
#pragma unroll
            for (int i = tid; i < 32 * 128 / 4; i += 256) dst[i] = src[i];
        }
        __syncthreads();
#pragma unroll 4
        for (int k = 0; k < 32; ++k) {
            float4 xa = *(const float4*)&Xs[k][tx * 4];
            float4 xb = *(const float4*)&Xs[k][64 + tx * 4];
            float xv[2][4] = {{xa.x, xa.y, xa.z, xa.w}, {xb.x, xb.y, xb.z, xb.w}};
            float wv[2][4];
#pragma unroll
            for (int c = 0; c < 2; ++c) {
                float4 w4 = *(const float4*)&Wsh[k][c * 64 + ty * 4];
                wv[c][0] = w4.x; wv[c][1] = w4.y; wv[c][2] = w4.z; wv[c][3] = w4.w;
            }
#pragma unroll
            for (int h = 0; h < 2; ++h)
#pragma unroll
                for (int c = 0; c < 2; ++c)
#pragma unroll
                    for (int i = 0; i < 4; ++i)
#pragma unroll
                        for (int j = 0; j < 4; ++j)
                            acc[h][c][i][j] = fmaf(xv[h][i], wv[c][j], acc[h][c][i][j]);
        }
        __syncthreads();
    }
#pragma unroll
    for (int h = 0; h < 2; ++h)
#pragma unroll
        for (int i = 0; i < 4; ++i) {
            int n = bm0 + h * 64 + tx * 4 + i;
            if (n < N) {
#pragma unroll
                for (int c = 0; c < 2; ++c) {
                    ushort4 o;
                    o.x = (unsigned short)f2bf(acc[h][c][i][0]);
                    o.y = (unsigned short)f2bf(acc[h][c][i][1]);
                    o.z = (unsigned short)f2bf(acc[h][c][i][2]);
                    o.w = (unsigned short)f2bf(acc[h][c][i][3]);
                    *(ushort4*)&H[(size_t)n * 128 + c * 64 + ty * 4] = o;
                }
            }
        }
}

// ---- exclusive scan of cnt[N] -> rowPtr[N+1], 1024 elems/block ----
__global__ __launch_bounds__(256) void scan_blocks(const int* __restrict__ cnt,
                                                   int* __restrict__ excl,
                                                   int* __restrict__ bsum, int N) {
    __shared__ int sh[256];
    int t = threadIdx.x;
    int base = blockIdx.x * 1024 + t * 4;
    int v0 = base + 0 < N ? cnt[base + 0] : 0;
    int v1 = base + 1 < N ? cnt[base + 1] : 0;
    int v2 = base + 2 < N ? cnt[base + 2] : 0;
    int v3 = base + 3 < N ? cnt[base + 3] : 0;
    int s = v0 + v1 + v2 + v3;
    sh[t] = s;
    __syncthreads();
    for (int off = 1; off < 256; off <<= 1) {
        int x = (t >= off) ? sh[t - off] : 0;
        __syncthreads();
        sh[t] += x;
        __syncthreads();
    }
    int incl = sh[t];
    int exclT = incl - s;
    if (t == 255) bsum[blockIdx.x] = incl;
    if (base + 0 < N) excl[base + 0] = exclT;
    if (base + 1 < N) excl[base + 1] = exclT + v0;
    if (base + 2 < N) excl[base + 2] = exclT + v0 + v1;
    if (base + 3 < N) excl[base + 3] = exclT + v0 + v1 + v2;
}

__global__ void scan_sums(int* __restrict__ bsum, int nb) {
    int run = 0;
    for (int i = 0; i < nb; ++i) { int v = bsum[i]; bsum[i] = run; run += v; }
    bsum[nb] = run;
}

__global__ __launch_bounds__(256) void scan_add(int* __restrict__ excl,
                                                const int* __restrict__ bsum,
                                                int N, int nb) {
    int i = blockIdx.x * 256 + threadIdx.x;
    if (i < N) excl[i] += bsum[i >> 10];
    if (i == 0) excl[N] = bsum[nb];
}

// ---- scatter edges into CSR pairs (src, RAW ew bits) — no atomics ----
__global__ __launch_bounds__(256) void scatter_kernel(const int* __restrict__ row,
                                                      const int* __restrict__ col,
                                                      const float* __restrict__ ew,
                                                      const int* __restrict__ rowPtr,
                                                      const int* __restrict__ eoff,
                                                      int2* __restrict__ csr, int E) {
    int e = blockIdx.x * 256 + threadIdx.x;
    if (e >= E) return;
    int c = col[e];
    csr[rowPtr[c] + eoff[e]] = make_int2(row[e], __float_as_int(ew[e]));
}

// ---- deg from CSR segment sum; dinv = rsqrt(deg + 1). 16 lanes per node ----
__global__ __launch_bounds__(256) void deg_dinv_kernel(const int* __restrict__ rowPtr,
                                                       const int2* __restrict__ csr,
                                                       float* __restrict__ dinv, int N) {
    int idx = blockIdx.x * 256 + threadIdx.x;
    int n = idx >> 4, l = idx & 15;
    if (n >= N) return;
    int beg = rowPtr[n], end = rowPtr[n + 1];
    float s = 0.f;
    for (int i = beg + l; i < end; i += 16) s += __int_as_float(csr[i].y);
#pragma unroll
    for (int off = 8; off; off >>= 1) s += __shfl_xor(s, off, 16);
    if (l == 0) dinv[n] = rsqrtf(s + 1.0f);
}

// ---- pre-normalize: csr.w = ew * dinv[src] (edge-parallel, streaming) ----
__global__ __launch_bounds__(256) void norm_csr_kernel(int2* __restrict__ csr,
                                                       const float* __restrict__ dinv, int E) {
    int i = blockIdx.x * 256 + threadIdx.x;
    if (i >= E) return;
    int2 p = csr[i];
    ((int*)csr)[2 * i + 1] = __float_as_int(__int_as_float(p.y) * dinv[p.x]);
}

// ---- layer 1 gather (bf16 H1, unroll-4 MLP) + self + bias + relu. Wave/node ----
__global__ __launch_bounds__(256) void agg_gather1(const int* __restrict__ rowPtr,
                                                   const int2* __restrict__ csr,
                                                   const unsigned* __restrict__ H1u,  // [N][64] bf16x2
                                                   const float* __restrict__ dinv,
                                                   const float2* __restrict__ b2,
                                                   float2* __restrict__ out2, int N) {
    int n = (blockIdx.x * 256 + threadIdx.x) >> 6;
    int lane = threadIdx.x & 63;
    if (n >= N) return;
    float dn = dinv[n];
    float accx = 0.f, accy = 0.f;
    int beg = rowPtr[n], end = rowPtr[n + 1];
    int j = beg;
    for (; j + 4 <= end; j += 4) {
        int2 p0 = csr[j + 0], p1 = csr[j + 1], p2 = csr[j + 2], p3 = csr[j + 3];
        unsigned v0 = H1u[(size_t)p0.x * 64 + lane];
        unsigned v1 = H1u[(size_t)p1.x * 64 + lane];
        unsigned v2 = H1u[(size_t)p2.x * 64 + lane];
        unsigned v3 = H1u[(size_t)p3.x * 64 + lane];
        float w0 = __int_as_float(p0.y), w1 = __int_as_float(p1.y);
        float w2 = __int_as_float(p2.y), w3 = __int_as_float(p3.y);
        accx += w0 * bf2f(v0 & 0xffffu); accy += w0 * bf2f(v0 >> 16);
        accx += w1 * bf2f(v1 & 0xffffu); accy += w1 * bf2f(v1 >> 16);
        accx += w2 * bf2f(v2 & 0xffffu); accy += w2 * bf2f(v2 >> 16);
        accx += w3 * bf2f(v3 & 0xffffu); accy += w3 * bf2f(v3 >> 16);
    }
    for (; j < end; ++j) {
        int2 p = csr[j];
        unsigned v = H1u[(size_t)p.x * 64 + lane];
        float w = __int_as_float(p.y);
        accx += w * bf2f(v & 0xffffu); accy += w * bf2f(v >> 16);
    }
    unsigned hv = H1u[(size_t)n * 64 + lane];
    float2 bb = b2[lane];
    float s = dn * dn;
    float2 o;
    o.x = fmaxf(fmaf(dn, accx, s * bf2f(hv & 0xffffu)) + bb.x, 0.f);
    o.y = fmaxf(fmaf(dn, accy, s * bf2f(hv >> 16)) + bb.y, 0.f);
    out2[(size_t)n * 64 + lane] = o;
}

// ---- H3[N x 64 bf16] = X[N x 128] @ W[128 x 64], BK=32, bf16 pack epilogue ----
__global__ __launch_bounds__(256) void gemm_tile64(const float* __restrict__ X,
                                                   const float* __restrict__ W,
                                                   unsigned short* __restrict__ H, int N) {
    __shared__ float Xs[32][128];
    __shared__ float Wsh[32][64];
    const int bm0 = blockIdx.x * 128;
    const int tid = threadIdx.x;
    const int tx = tid & 15, ty = tid >> 4;
    float acc[2][4][4] = {};
    for (int kc = 0; kc < 4; ++kc) {
        {
            int r = tid >> 1;
            int k0 = (tid & 1) * 16;
            int node = min(bm0 + r, N - 1);
            const float4* src = (const float4*)(X + (size_t)node * 128 + kc * 32 + k0);
#pragma unroll
            for (int j4 = 0; j4 < 4; ++j4) {
                float4 v = src[j4];
                int k = k0 + j4 * 4;
                Xs[k + 0][r] = v.x;
                Xs[k + 1][r] = v.y;
                Xs[k + 2][r] = v.z;
                Xs[k + 3][r] = v.w;
            }
        }
        {
            const float4* src = (const float4*)(W + (size_t)kc * 32 * 64);
            float4* dst = (float4*)&Wsh[0][0];
#pragma unroll
            for (int i = tid; i < 32 * 64 / 4; i += 256) dst[i] = src[i];
        }
        __syncthreads();
#pragma unroll 4
        for (int k = 0; k < 32; ++k) {
            float4 xa = *(const float4*)&Xs[k][tx * 4];
            float4 xb = *(const float4*)&Xs[k][64 + tx * 4];
            float xv[2][4] = {{xa.x, xa.y, xa.z, xa.w}, {xb.x, xb.y, xb.z, xb.w}};
            float4 w4 = *(const float4*)&Wsh[k][ty * 4];
            float wv[4] = {w4.x, w4.y, w4.z, w4.w};
#pragma unroll
            for (int h = 0; h < 2; ++h)
#pragma unroll
                for (int i = 0; i < 4; ++i)
#pragma unroll
                    for (int j = 0; j < 4; ++j)
                        acc[h][i][j] = fmaf(xv[h][i], wv[j], acc[h][i][j]);
        }
        __syncthreads();
    }
#pragma unroll
    for (int h = 0; h < 2; ++h)
#pragma unroll
        for (int i = 0; i < 4; ++i) {
            int n = bm0 + h * 64 + tx * 4 + i;
            if (n < N) {
                ushort4 o;
                o.x = (unsigned short)f2bf(acc[h][i][0]);
                o.y = (unsigned short)f2bf(acc[h][i][1]);
                o.z = (unsigned short)f2bf(acc[h][i][2]);
                o.w = (unsigned short)f2bf(acc[h][i][3]);
                *(ushort4*)&H[(size_t)n * 64 + ty * 4] = o;
            }
        }
}

// ---- layer 2 gather (bf16 H3) + self + bias + L2 norm. 32 lanes/node, 2 nodes/wave ----
__global__ __launch_bounds__(256) void agg_gather2(const int* __restrict__ rowPtr,
                                                   const int2* __restrict__ csr,
                                                   const unsigned* __restrict__ H3u,  // [N][32] bf16x2
                                                   const float* __restrict__ dinv,
                                                   const float2* __restrict__ b2,
                                                   float2* __restrict__ out2, int N) {
    int n = (blockIdx.x * 256 + threadIdx.x) >> 5;
    int l = threadIdx.x & 31;
    if (n >= N) return;
    float dn = dinv[n];
    float accx = 0.f, accy = 0.f;
    int beg = rowPtr[n], end = rowPtr[n + 1];
    int j = beg;
    for (; j + 4 <= end; j += 4) {
        int2 p0 = csr[j + 0], p1 = csr[j + 1], p2 = csr[j + 2], p3 = csr[j + 3];
        unsigned v0 = H3u[(size_t)p0.x * 32 + l];
        unsigned v1 = H3u[(size_t)p1.x * 32 + l];
        unsigned v2 = H3u[(size_t)p2.x * 32 + l];
        unsigned v3 = H3u[(size_t)p3.x * 32 + l];
        float w0 = __int_as_float(p0.y), w1 = __int_as_float(p1.y);
        float w2 = __int_as_float(p2.y), w3 = __int_as_float(p3.y);
        accx += w0 * bf2f(v0 & 0xffffu); accy += w0 * bf2f(v0 >> 16);
        accx += w1 * bf2f(v1 & 0xffffu); accy += w1 * bf2f(v1 >> 16);
        accx += w2 * bf2f(v2 & 0xffffu); accy += w2 * bf2f(v2 >> 16);
        accx += w3 * bf2f(v3 & 0xffffu); accy += w3 * bf2f(v3 >> 16);
    }
    for (; j < end; ++j) {
        int2 p = csr[j];
        unsigned v = H3u[(size_t)p.x * 32 + l];
        float w = __int_as_float(p.y);
        accx += w * bf2f(v & 0xffffu); accy += w * bf2f(v >> 16);
    }
    unsigned hv = H3u[(size_t)n * 32 + l];
    float2 bb = b2[l];
    float s = dn * dn;
    float vx = fmaf(dn, accx, s * bf2f(hv & 0xffffu)) + bb.x;
    float vy = fmaf(dn, accy, s * bf2f(hv >> 16)) + bb.y;
    float ss = vx * vx + vy * vy;
#pragma unroll
    for (int off = 16; off; off >>= 1) ss += __shfl_xor(ss, off, 64);  // stays in 32-group
    float scale = 1.0f / fmaxf(sqrtf(ss), 1e-12f);
    out2[(size_t)n * 32 + l] = make_float2(vx * scale, vy * scale);
}

extern "C" void kernel_launch(void* const* d_in, const int* in_sizes, int n_in,
                              void* d_out, int out_size, void* d_ws, size_t ws_size,
                              hipStream_t stream) {
    const float* x  = (const float*)d_in[0];
    const int*   ei = (const int*)d_in[1];
    const float* ew = (const float*)d_in[2];
    const float* W1 = (const float*)d_in[3];
    const float* b1 = (const float*)d_in[4];
    const float* W2 = (const float*)d_in[5];
    const float* b2 = (const float*)d_in[6];
    float* out = (float*)d_out;
    const int N = in_sizes[0] / NF;
    const int E = in_sizes[2];
    const int* row = ei;
    const int* col = ei + E;
    const int NB = (N + 1023) / 1024;

    char* ws = (char*)d_ws;
    size_t off = 0;
    auto take = [&](size_t bytes) {
        char* p = ws + off;
        off = (off + bytes + 255) & ~(size_t)255;
        return p;
    };
    float* dinv   = (float*)take((size_t)N * 4);
    int*   cnt    = (int*)  take((size_t)N * 4);
    int*   rowPtr = (int*)  take((size_t)(N + 1) * 4);
    int*   eoff   = (int*)  take((size_t)E * 4);
    int*   bsum   = (int*)  take((size_t)(NB + 1) * 4);
    int2*  csr    = (int2*) take((size_t)E * 8);
    unsigned short* H1 = (unsigned short*)take((size_t)N * NF * 2);  // bf16
    float* buf2   = (float*)take((size_t)N * NF * 4);  // relu output (fp32)
    unsigned short* H3 = (unsigned short*)take((size_t)N * NC * 2);  // bf16

    hipMemsetAsync(cnt, 0, (size_t)N * 4, stream);

    // fused: edge counting+eoff (atomic-bound) || GEMM1 (VALU/LDS-bound)
    const int CB = 256;
    const int GB = (N + 127) / 128;
    gemm1_cnt_fused<<<CB + GB, 256, 0, stream>>>(x, W1, H1, col, cnt, eoff, N, E, CB);

    // CSR build (atomic-free scatter)
    scan_blocks<<<NB, 256, 0, stream>>>(cnt, rowPtr, bsum, N);
    scan_sums<<<1, 1, 0, stream>>>(bsum, NB);
    scan_add<<<(N + 255) / 256, 256, 0, stream>>>(rowPtr, bsum, N, NB);
    scatter_kernel<<<(E + 255) / 256, 256, 0, stream>>>(row, col, ew, rowPtr, eoff, csr, E);

    // degree -> dinv -> pre-normalized weights (ew * dinv[src])
    deg_dinv_kernel<<<(N * 16 + 255) / 256, 256, 0, stream>>>(rowPtr, csr, dinv, N);
    norm_csr_kernel<<<(E + 255) / 256, 256, 0, stream>>>(csr, dinv, E);

    // layer 1 aggregation (bf16 gathers, unroll-4) + bias + relu
    agg_gather1<<<(N * 64 + 255) / 256, 256, 0, stream>>>(rowPtr, csr, (const unsigned*)H1,
                                                          dinv, (const float2*)b1,
                                                          (float2*)buf2, N);

    // layer 2: GEMM (fp32 -> bf16) ; gather + bias + l2norm
    gemm_tile64<<<(N + 127) / 128, 256, 0, stream>>>(buf2, W2, H3, N);
    agg_gather2<<<(N * 32 + 255) / 256, 256, 0, stream>>>(rowPtr, csr, (const unsigned*)H3,
                                                          dinv, (const float2*)b2,
                                                          (float2*)out, N);
}

// Round 7
// 174.437 us; speedup vs baseline: 12.9785x; 1.0039x over previous
//
#include <hip/hip_runtime.h>

#define NF 128   // in/hidden features
#define NC 64    // classes
#define SLICES 64

__device__ __forceinline__ unsigned f2bf(float f) {   // fp32 -> bf16 (RTN)
    unsigned u = __float_as_uint(f);
    return (u + 0x7FFFu + ((u >> 16) & 1u)) >> 16;
}
__device__ __forceinline__ float bf2f(unsigned h) { return __uint_as_float(h << 16); }

// ---- LDS-privatized count+rank: 2 node-halves x SLICES edge-slices.
// hist packs two 16-bit counters per word; atomicAdd returns rank for free.
// Requires nodes-per-half <= 25088 (N <= 50176).
__global__ __launch_bounds__(256) void count_rank_kernel(const int* __restrict__ col,
                                                         unsigned short* __restrict__ eoff16,
                                                         unsigned short* __restrict__ C16,
                                                         int N, int E, int SL, int nh) {
    __shared__ unsigned hist[12544];
    const int j = blockIdx.x >> 1;   // slice
    const int h = blockIdx.x & 1;    // node half
    const int nlo = h * nh;
    const int nhi = min(N, nlo + nh);
    const int words = (nhi - nlo + 1) >> 1;
    for (int i = threadIdx.x; i < words; i += 256) hist[i] = 0;
    __syncthreads();
    const int e0 = j * SL, e1 = min(E, e0 + SL);
    for (int e = e0 + threadIdx.x; e < e1; e += 256) {
        int c = col[e];
        if (c >= nlo && c < nhi) {
            int cl = c - nlo;
            unsigned sh = (cl & 1) * 16;
            unsigned old = atomicAdd(&hist[cl >> 1], 1u << sh);
            eoff16[e] = (unsigned short)((old >> sh) & 0xffffu);
        }
    }
    __syncthreads();
    // write packed counts (word-aligned: N even, nh even)
    unsigned* Cw = (unsigned*)(C16 + (size_t)j * N + nlo);
    for (int i = threadIdx.x; i < words; i += 256) Cw[i] = hist[i];
}

// ---- per-node exclusive scan over slices (in place) + totals ----
__global__ __launch_bounds__(256) void scanC_kernel(unsigned short* __restrict__ C16,
                                                    int* __restrict__ tot, int N) {
    int n = blockIdx.x * 256 + threadIdx.x;
    if (n >= N) return;
    int t = 0;
#pragma unroll 4
    for (int j = 0; j < SLICES; ++j) {
        size_t idx = (size_t)j * N + n;
        int v = C16[idx];
        C16[idx] = (unsigned short)t;
        t += v;
    }
    tot[n] = t;
}

// ---- exclusive scan of tot[N] -> rowPtr[N+1], 1024 elems/block ----
__global__ __launch_bounds__(256) void scan_blocks(const int* __restrict__ cnt,
                                                   int* __restrict__ excl,
                                                   int* __restrict__ bsum, int N) {
    __shared__ int sh[256];
    int t = threadIdx.x;
    int base = blockIdx.x * 1024 + t * 4;
    int v0 = base + 0 < N ? cnt[base + 0] : 0;
    int v1 = base + 1 < N ? cnt[base + 1] : 0;
    int v2 = base + 2 < N ? cnt[base + 2] : 0;
    int v3 = base + 3 < N ? cnt[base + 3] : 0;
    int s = v0 + v1 + v2 + v3;
    sh[t] = s;
    __syncthreads();
    for (int off = 1; off < 256; off <<= 1) {
        int x = (t >= off) ? sh[t - off] : 0;
        __syncthreads();
        sh[t] += x;
        __syncthreads();
    }
    int incl = sh[t];
    int exclT = incl - s;
    if (t == 255) bsum[blockIdx.x] = incl;
    if (base + 0 < N) excl[base + 0] = exclT;
    if (base + 1 < N) excl[base + 1] = exclT + v0;
    if (base + 2 < N) excl[base + 2] = exclT + v0 + v1;
    if (base + 3 < N) excl[base + 3] = exclT + v0 + v1 + v2;
}

__global__ void scan_sums(int* __restrict__ bsum, int nb) {
    int run = 0;
    for (int i = 0; i < nb; ++i) { int v = bsum[i]; bsum[i] = run; run += v; }
    bsum[nb] = run;
}

__global__ __launch_bounds__(256) void scan_add(int* __restrict__ excl,
                                                const int* __restrict__ bsum,
                                                int N, int nb) {
    int i = blockIdx.x * 256 + threadIdx.x;
    if (i < N) excl[i] += bsum[i >> 10];
    if (i == 0) excl[N] = bsum[nb];
}

// ---- fused: scatter-role blocks (CSR permutation, no atomics) + gemm1-role (H1=X@W1, bf16) ----
__global__ __launch_bounds__(256) void scatter_gemm1_fused(const int* __restrict__ row,
                                                           const int* __restrict__ col,
                                                           const float* __restrict__ ew,
                                                           const int* __restrict__ rowPtr,
                                                           const unsigned short* __restrict__ Coff16,
                                                           const unsigned short* __restrict__ eoff16,
                                                           int2* __restrict__ csr,
                                                           const float* __restrict__ X,
                                                           const float* __restrict__ W,
                                                           unsigned short* __restrict__ H,
                                                           int N, int E, int SL, int SB) {
    __shared__ float Xs[32][64];
    __shared__ float Wsh[32][128];
    if ((int)blockIdx.x < SB) {
        int stride = SB * 256;
        for (int e = blockIdx.x * 256 + threadIdx.x; e < E; e += stride) {
            int c = col[e];
            int j = e / SL;
            int idx = rowPtr[c] + (int)Coff16[(size_t)j * N + c] + (int)eoff16[e];
            csr[idx] = make_int2(row[e], __float_as_int(ew[e]));
        }
        return;
    }
    const int bm0 = (blockIdx.x - SB) * 64;
    const int tid = threadIdx.x;
    const int tx = tid & 15, ty = tid >> 4;
    float acc[4][8] = {};
    for (int kc = 0; kc < 4; ++kc) {
        {   // stage X transposed: 64 nodes x 32 k
            int r = tid >> 2, q = tid & 3;
            int node = min(bm0 + r, N - 1);
            const float4* src = (const float4*)(X + (size_t)node * 128 + kc * 32);
#pragma unroll
            for (int qq = 0; qq < 2; ++qq) {
                float4 v = src[q + qq * 4];
                int k = (q + qq * 4) * 4;
                Xs[k + 0][r] = v.x;
                Xs[k + 1][r] = v.y;
                Xs[k + 2][r] = v.z;
                Xs[k + 3][r] = v.w;
            }
        }
        {   // stage W rows kc*32..+31, full 128 wide
            const float4* src = (const float4*)(W + (size_t)kc * 32 * 128);
            float4* dst = (float4*)&Wsh[0][0];
#pragma unroll
            for (int i = tid; i < 1024; i += 256) dst[i] = src[i];
        }
        __syncthreads();
#pragma unroll 4
        for (int k = 0; k < 32; ++k) {
            float4 xa = *(const float4*)&Xs[k][tx * 4];
            float4 wA = *(const float4*)&Wsh[k][ty * 8];
            float4 wB = *(const float4*)&Wsh[k][ty * 8 + 4];
            float xv[4] = {xa.x, xa.y, xa.z, xa.w};
            float wv[8] = {wA.x, wA.y, wA.z, wA.w, wB.x, wB.y, wB.z, wB.w};
#pragma unroll
            for (int i = 0; i < 4; ++i)
#pragma unroll
                for (int j = 0; j < 8; ++j)
                    acc[i][j] = fmaf(xv[i], wv[j], acc[i][j]);
        }
        __syncthreads();
    }
#pragma unroll
    for (int i = 0; i < 4; ++i) {
        int n = bm0 + tx * 4 + i;
        if (n < N) {
            ushort4 oA, oB;
            oA.x = (unsigned short)f2bf(acc[i][0]); oA.y = (unsigned short)f2bf(acc[i][1]);
            oA.z = (unsigned short)f2bf(acc[i][2]); oA.w = (unsigned short)f2bf(acc[i][3]);
            oB.x = (unsigned short)f2bf(acc[i][4]); oB.y = (unsigned short)f2bf(acc[i][5]);
            oB.z = (unsigned short)f2bf(acc[i][6]); oB.w = (unsigned short)f2bf(acc[i][7]);
            *(ushort4*)&H[(size_t)n * 128 + ty * 8] = oA;
            *(ushort4*)&H[(size_t)n * 128 + ty * 8 + 4] = oB;
        }
    }
}

// ---- deg from CSR segment sum; dinv = rsqrt(deg + 1). 16 lanes per node ----
__global__ __launch_bounds__(256) void deg_dinv_kernel(const int* __restrict__ rowPtr,
                                                       const int2* __restrict__ csr,
                                                       float* __restrict__ dinv, int N) {
    int idx = blockIdx.x * 256 + threadIdx.x;
    int n = idx >> 4, l = idx & 15;
    if (n >= N) return;
    int beg = rowPtr[n], end = rowPtr[n + 1];
    float s = 0.f;
    for (int i = beg + l; i < end; i += 16) s += __int_as_float(csr[i].y);
#pragma unroll
    for (int off = 8; off; off >>= 1) s += __shfl_xor(s, off, 16);
    if (l == 0) dinv[n] = rsqrtf(s + 1.0f);
}

// ---- pre-normalize: csr.w = ew * dinv[src] (edge-parallel, streaming) ----
__global__ __launch_bounds__(256) void norm_csr_kernel(int2* __restrict__ csr,
                                                       const float* __restrict__ dinv, int E) {
    int i = blockIdx.x * 256 + threadIdx.x;
    if (i >= E) return;
    int2 p = csr[i];
    ((int*)csr)[2 * i + 1] = __float_as_int(__int_as_float(p.y) * dinv[p.x]);
}

// ---- layer 1 gather (bf16 H1, unroll-4 MLP) + self + bias + relu. Wave/node ----
__global__ __launch_bounds__(256) void agg_gather1(const int* __restrict__ rowPtr,
                                                   const int2* __restrict__ csr,
                                                   const unsigned* __restrict__ H1u,  // [N][64] bf16x2
                                                   const float* __restrict__ dinv,
                                                   const float2* __restrict__ b2,
                                                   float2* __restrict__ out2, int N) {
    int n = (blockIdx.x * 256 + threadIdx.x) >> 6;
    int lane = threadIdx.x & 63;
    if (n >= N) return;
    float dn = dinv[n];
    float accx = 0.f, accy = 0.f;
    int beg = rowPtr[n], end = rowPtr[n + 1];
    int j = beg;
    for (; j + 4 <= end; j += 4) {
        int2 p0 = csr[j + 0], p1 = csr[j + 1], p2 = csr[j + 2], p3 = csr[j + 3];
        unsigned v0 = H1u[(size_t)p0.x * 64 + lane];
        unsigned v1 = H1u[(size_t)p1.x * 64 + lane];
        unsigned v2 = H1u[(size_t)p2.x * 64 + lane];
        unsigned v3 = H1u[(size_t)p3.x * 64 + lane];
        float w0 = __int_as_float(p0.y), w1 = __int_as_float(p1.y);
        float w2 = __int_as_float(p2.y), w3 = __int_as_float(p3.y);
        accx += w0 * bf2f(v0 & 0xffffu); accy += w0 * bf2f(v0 >> 16);
        accx += w1 * bf2f(v1 & 0xffffu); accy += w1 * bf2f(v1 >> 16);
        accx += w2 * bf2f(v2 & 0xffffu); accy += w2 * bf2f(v2 >> 16);
        accx += w3 * bf2f(v3 & 0xffffu); accy += w3 * bf2f(v3 >> 16);
    }
    for (; j < end; ++j) {
        int2 p = csr[j];
        unsigned v = H1u[(size_t)p.x * 64 + lane];
        float w = __int_as_float(p.y);
        accx += w * bf2f(v & 0xffffu); accy += w * bf2f(v >> 16);
    }
    unsigned hv = H1u[(size_t)n * 64 + lane];
    float2 bb = b2[lane];
    float s = dn * dn;
    float2 o;
    o.x = fmaxf(fmaf(dn, accx, s * bf2f(hv & 0xffffu)) + bb.x, 0.f);
    o.y = fmaxf(fmaf(dn, accy, s * bf2f(hv >> 16)) + bb.y, 0.f);
    out2[(size_t)n * 64 + lane] = o;
}

// ---- H3[N x 64 bf16] = X[N x 128] @ W[128 x 64], BM=64, BK=32 ----
__global__ __launch_bounds__(256) void gemm_tile64(const float* __restrict__ X,
                                                   const float* __restrict__ W,
                                                   unsigned short* __restrict__ H, int N) {
    __shared__ float Xs[32][64];
    __shared__ float Wsh[32][64];
    const int bm0 = blockIdx.x * 64;
    const int tid = threadIdx.x;
    const int tx = tid & 15, ty = tid >> 4;
    float acc[4][4] = {};
    for (int kc = 0; kc < 4; ++kc) {
        {
            int r = tid >> 2, q = tid & 3;
            int node = min(bm0 + r, N - 1);
            const float4* src = (const float4*)(X + (size_t)node * 128 + kc * 32);
#pragma unroll
            for (int qq = 0; qq < 2; ++qq) {
                float4 v = src[q + qq * 4];
                int k = (q + qq * 4) * 4;
                Xs[k + 0][r] = v.x;
                Xs[k + 1][r] = v.y;
                Xs[k + 2][r] = v.z;
                Xs[k + 3][r] = v.w;
            }
        }
        {
            const float4* src = (const float4*)(W + (size_t)kc * 32 * 64);
            float4* dst = (float4*)&Wsh[0][0];
#pragma unroll
            for (int i = tid; i < 512; i += 256) dst[i] = src[i];
        }
        __syncthreads();
#pragma unroll 4
        for (int k = 0; k < 32; ++k) {
            float4 xa = *(const float4*)&Xs[k][tx * 4];
            float4 w4 = *(const float4*)&Wsh[k][ty * 4];
            float xv[4] = {xa.x, xa.y, xa.z, xa.w};
            float wv[4] = {w4.x, w4.y, w4.z, w4.w};
#pragma unroll
            for (int i = 0; i < 4; ++i)
#pragma unroll
                for (int j = 0; j < 4; ++j)
                    acc[i][j] = fmaf(xv[i], wv[j], acc[i][j]);
        }
        __syncthreads();
    }
#pragma unroll
    for (int i = 0; i < 4; ++i) {
        int n = bm0 + tx * 4 + i;
        if (n < N) {
            ushort4 o;
            o.x = (unsigned short)f2bf(acc[i][0]);
            o.y = (unsigned short)f2bf(acc[i][1]);
            o.z = (unsigned short)f2bf(acc[i][2]);
            o.w = (unsigned short)f2bf(acc[i][3]);
            *(ushort4*)&H[(size_t)n * 64 + ty * 4] = o;
        }
    }
}

// ---- layer 2 gather (bf16 H3) + self + bias + L2 norm. 32 lanes/node, 2 nodes/wave ----
__global__ __launch_bounds__(256) void agg_gather2(const int* __restrict__ rowPtr,
                                                   const int2* __restrict__ csr,
                                                   const unsigned* __restrict__ H3u,  // [N][32] bf16x2
                                                   const float* __restrict__ dinv,
                                                   const float2* __restrict__ b2,
                                                   float2* __restrict__ out2, int N) {
    int n = (blockIdx.x * 256 + threadIdx.x) >> 5;
    int l = threadIdx.x & 31;
    if (n >= N) return;
    float dn = dinv[n];
    float accx = 0.f, accy = 0.f;
    int beg = rowPtr[n], end = rowPtr[n + 1];
    int j = beg;
    for (; j + 4 <= end; j += 4) {
        int2 p0 = csr[j + 0], p1 = csr[j + 1], p2 = csr[j + 2], p3 = csr[j + 3];
        unsigned v0 = H3u[(size_t)p0.x * 32 + l];
        unsigned v1 = H3u[(size_t)p1.x * 32 + l];
        unsigned v2 = H3u[(size_t)p2.x * 32 + l];
        unsigned v3 = H3u[(size_t)p3.x * 32 + l];
        float w0 = __int_as_float(p0.y), w1 = __int_as_float(p1.y);
        float w2 = __int_as_float(p2.y), w3 = __int_as_float(p3.y);
        accx += w0 * bf2f(v0 & 0xffffu); accy += w0 * bf2f(v0 >> 16);
        accx += w1 * bf2f(v1 & 0xffffu); accy += w1 * bf2f(v1 >> 16);
        accx += w2 * bf2f(v2 & 0xffffu); accy += w2 * bf2f(v2 >> 16);
        accx += w3 * bf2f(v3 & 0xffffu); accy += w3 * bf2f(v3 >> 16);
    }
    for (; j < end; ++j) {
        int2 p = csr[j];
        unsigned v = H3u[(size_t)p.x * 32 + l];
        float w = __int_as_float(p.y);
        accx += w * bf2f(v & 0xffffu); accy += w * bf2f(v >> 16);
    }
    unsigned hv = H3u[(size_t)n * 32 + l];
    float2 bb = b2[l];
    float s = dn * dn;
    float vx = fmaf(dn, accx, s * bf2f(hv & 0xffffu)) + bb.x;
    float vy = fmaf(dn, accy, s * bf2f(hv >> 16)) + bb.y;
    float ss = vx * vx + vy * vy;
#pragma unroll
    for (int off = 16; off; off >>= 1) ss += __shfl_xor(ss, off, 64);  // stays in 32-group
    float scale = 1.0f / fmaxf(sqrtf(ss), 1e-12f);
    out2[(size_t)n * 32 + l] = make_float2(vx * scale, vy * scale);
}

extern "C" void kernel_launch(void* const* d_in, const int* in_sizes, int n_in,
                              void* d_out, int out_size, void* d_ws, size_t ws_size,
                              hipStream_t stream) {
    const float* x  = (const float*)d_in[0];
    const int*   ei = (const int*)d_in[1];
    const float* ew = (const float*)d_in[2];
    const float* W1 = (const float*)d_in[3];
    const float* b1 = (const float*)d_in[4];
    const float* W2 = (const float*)d_in[5];
    const float* b2 = (const float*)d_in[6];
    float* out = (float*)d_out;
    const int N = in_sizes[0] / NF;
    const int E = in_sizes[2];
    const int* row = ei;
    const int* col = ei + E;
    const int NB = (N + 1023) / 1024;
    const int SL = (E + SLICES - 1) / SLICES;   // edges per slice
    const int nh = (N + 1) / 2;                 // nodes per half (<= 25088)

    char* ws = (char*)d_ws;
    size_t off = 0;
    auto take = [&](size_t bytes) {
        char* p = ws + off;
        off = (off + bytes + 255) & ~(size_t)255;
        return p;
    };
    float* dinv   = (float*)take((size_t)N * 4);
    int*   tot    = (int*)  take((size_t)N * 4);
    int*   rowPtr = (int*)  take((size_t)(N + 1) * 4);
    unsigned short* eoff16 = (unsigned short*)take((size_t)E * 2);
    int*   bsum   = (int*)  take((size_t)(NB + 1) * 4);
    unsigned short* C16    = (unsigned short*)take((size_t)SLICES * N * 2);
    int2*  csr    = (int2*) take((size_t)E * 8);
    unsigned short* H1 = (unsigned short*)take((size_t)N * NF * 2);  // bf16; reused as H3
    float* buf2   = (float*)take((size_t)N * NF * 4);                // relu output (fp32)
    unsigned short* H3 = H1;                                         // [N][64] bf16, after agg1

    // count + per-(slice,node) ranks — all atomics confined to LDS
    count_rank_kernel<<<2 * SLICES, 256, 0, stream>>>(col, eoff16, C16, N, E, SL, nh);
    scanC_kernel<<<(N + 255) / 256, 256, 0, stream>>>(C16, tot, N);
    scan_blocks<<<NB, 256, 0, stream>>>(tot, rowPtr, bsum, N);
    scan_sums<<<1, 1, 0, stream>>>(bsum, NB);
    scan_add<<<(N + 255) / 256, 256, 0, stream>>>(rowPtr, bsum, N, NB);

    // fused: CSR scatter (streaming, no atomics) || GEMM1 (VALU/LDS-bound)
    const int SB = 128;
    const int GB = (N + 63) / 64;
    scatter_gemm1_fused<<<SB + GB, 256, 0, stream>>>(row, col, ew, rowPtr, C16, eoff16,
                                                     csr, x, W1, H1, N, E, SL, SB);

    // degree -> dinv -> pre-normalized weights (ew * dinv[src])
    deg_dinv_kernel<<<(N * 16 + 255) / 256, 256, 0, stream>>>(rowPtr, csr, dinv, N);
    norm_csr_kernel<<<(E + 255) / 256, 256, 0, stream>>>(csr, dinv, E);

    // layer 1 aggregation (bf16 gathers, unroll-4) + bias + relu
    agg_gather1<<<(N * 64 + 255) / 256, 256, 0, stream>>>(rowPtr, csr, (const unsigned*)H1,
                                                          dinv, (const float2*)b1,
                                                          (float2*)buf2, N);

    // layer 2: GEMM (fp32 -> bf16) ; gather + bias + l2norm
    gemm_tile64<<<(N + 63) / 64, 256, 0, stream>>>(buf2, W2, H3, N);
    agg_gather2<<<(N * 32 + 255) / 256, 256, 0, stream>>>(rowPtr, csr, (const unsigned*)H3,
                                                          dinv, (const float2*)b2,
                                                          (float2*)out, N);
}